// Round 10
// baseline (305.945 us; speedup 1.0000x reference)
//
#include <hip/hip_runtime.h>

#define KNB 32
#define CIN 128
#define CH 64
#define COUT 256
#define BN_EPS 1e-5f
#define CONV_GRID 256

typedef __attribute__((ext_vector_type(8))) short bf16x8;
typedef __attribute__((ext_vector_type(4))) float f32x4;

static __device__ __forceinline__ float leakyf(float v){ return fmaxf(v, 0.1f*v); }

static __device__ __forceinline__ unsigned short f2bf(float f){
    unsigned u = __float_as_uint(f);
    u += 0x7FFFu + ((u >> 16) & 1u);
    return (unsigned short)(u >> 16);
}
static __device__ __forceinline__ float bf2f(ushort u){ return __uint_as_float(((unsigned)u) << 16); }

static __device__ __forceinline__ unsigned cvtpk(float lo, float hi){
    unsigned r;
    asm("v_cvt_pk_bf16_f32 %0, %1, %2" : "=v"(r) : "v"(lo), "v"(hi));
    return r;
}

// per-wave BN affine from SYMMETRIC Gram/colsum; coalesced: lane indexes the
// contiguous dim of G (pq = w^T G^T w = w^T G w). W[i*M+o] inner reads are
// wave-uniform broadcasts. G is L1/L2-resident (16-64KB).
static __device__ __forceinline__ void bn_affine_wave(const float* __restrict__ G, const float* __restrict__ s,
    const float* __restrict__ W, const float* __restrict__ gg, const float* __restrict__ bb,
    float invcnt, int D, int M, int o, int lane, float& ai, float& ci)
{
    float pm = 0.f, pq = 0.f;
    for (int j = lane; j < D; j += 64){
        float wj = W[j*M + o];
        pm += s[j]*wj;
        float t = 0.f;
        for (int i = 0; i < D; ++i) t += G[i*D + j]*W[i*M + o];
        pq += wj*t;
    }
    #pragma unroll
    for (int off = 32; off; off >>= 1){
        pm += __shfl_down(pm, off);
        pq += __shfl_down(pq, off);
    }
    float m  = pm*invcnt;
    float var = pq*invcnt - m*m;
    float a_ = gg[o]*rsqrtf(var + BN_EPS);
    float c_ = bb[o] - m*a_;
    ai = __shfl(a_, 0);
    ci = __shfl(c_, 0);
}

// ---------- K1 split-grid: [0,128) gram128 partials from fp32 feat ; [128,256) cvt+hist+w1s+shadow ----------
__global__ __launch_bounds__(512) void k1_kernel(const float* __restrict__ feat, const int* __restrict__ inds,
    const float* __restrict__ W1, int N,
    float* __restrict__ slabA, ushort* __restrict__ featbf, ushort* __restrict__ w1s,
    ushort* __restrict__ xbf, float* __restrict__ cnt)
{
    __shared__ ushort Xt[128][40];
    __shared__ float red[16][128];
    int tid = threadIdx.x, bid = blockIdx.x;
    if (bid < 128){
        int wave = tid >> 6, lane = tid & 63, l15 = lane & 15, g = lane >> 4;
        int wr = wave >> 1, wc = wave & 1;
        const f32x4 z4 = {0.f,0.f,0.f,0.f};
        f32x4 acc[2][4];
        #pragma unroll
        for (int i=0;i<2;++i)
            #pragma unroll
            for (int j=0;j<4;++j) acc[i][j] = z4;
        float pcs[4] = {0,0,0,0};
        int nch = (N + 31) >> 5;
        for (int ch = bid; ch < nch; ch += 128){
            int base = ch << 5;
            __syncthreads();
            #pragma unroll
            for (int ii=0; ii<2; ++ii){
                int i = tid + ii*512;
                int r = i >> 5, c4 = i & 31;
                int n = base + r;
                float4 v = make_float4(0.f,0.f,0.f,0.f);
                if (n < N) v = ((const float4*)feat)[(size_t)n*32 + c4];
                ushort b0=f2bf(v.x), b1=f2bf(v.y), b2=f2bf(v.z), b3=f2bf(v.w);
                Xt[c4*4+0][r]=b0; Xt[c4*4+1][r]=b1; Xt[c4*4+2][r]=b2; Xt[c4*4+3][r]=b3;
                pcs[0]+=bf2f(b0); pcs[1]+=bf2f(b1); pcs[2]+=bf2f(b2); pcs[3]+=bf2f(b3);
            }
            __syncthreads();
            bf16x8 af[2], bv[4];
            #pragma unroll
            for (int t=0;t<2;++t) af[t] = *(const bf16x8*)&Xt[wr*32 + t*16 + l15][g*8];
            #pragma unroll
            for (int u=0;u<4;++u) bv[u] = *(const bf16x8*)&Xt[wc*64 + u*16 + l15][g*8];
            #pragma unroll
            for (int t=0;t<2;++t)
                #pragma unroll
                for (int u=0;u<4;++u)
                    acc[t][u] = __builtin_amdgcn_mfma_f32_16x16x32_bf16(af[t], bv[u], acc[t][u], 0,0,0);
        }
        float* Gp = slabA + (size_t)bid*16512;
        #pragma unroll
        for (int t=0;t<2;++t)
            #pragma unroll
            for (int u=0;u<4;++u)
                #pragma unroll
                for (int q=0;q<4;++q)
                    Gp[(wr*32 + t*16 + g*4 + q)*CIN + wc*64 + u*16 + l15] = acc[t][u][q];
        __syncthreads();
        { int r16 = tid >> 5, c4 = tid & 31;
          #pragma unroll
          for (int j=0;j<4;++j) red[r16][c4*4+j] = pcs[j]; }
        __syncthreads();
        if (tid < CIN){
            float s = 0.f;
            #pragma unroll
            for (int k=0;k<16;++k) s += red[k][tid];
            Gp[16384 + tid] = s;
        }
    } else {
        int t2 = (bid-128)*512 + tid;
        const int TG = 128*512;
        for (int i = t2; i < N*32; i += TG){
            float4 v = ((const float4*)feat)[i];
            uint2 pk; pk.x = cvtpk(v.x, v.y); pk.y = cvtpk(v.z, v.w);
            ((uint2*)featbf)[i] = pk;
        }
        for (int i = t2; i < N*KNB; i += TG){
            int ix = inds[i];
            if ((unsigned)ix < (unsigned)N) atomicAdd(&cnt[ix], 1.0f);
        }
        if (t2 < 192*CH){
            int r = t2 >> 6, dd = t2 & 63;
            int c = r >> 6, h = r & 63;
            w1s[t2] = f2bf(W1[dd*192 + 3*h + c]);
        }
        if (t2 < CH) xbf[(size_t)N*CH + t2] = 0;
    }
}

// ---------- reduce per-block partial slabs (4 independent accumulator chains) ----------
__global__ __launch_bounds__(256) void reduce_slab(const float* __restrict__ slab, int nparts, int len,
                                                   float* __restrict__ dst)
{
    int j = blockIdx.x*256 + threadIdx.x;
    if (j < len){
        float s0 = 0.f, s1 = 0.f, s2 = 0.f, s3 = 0.f;
        int b = 0;
        for (; b + 4 <= nparts; b += 4){
            s0 += slab[(size_t)(b+0)*len + j];
            s1 += slab[(size_t)(b+1)*len + j];
            s2 += slab[(size_t)(b+2)*len + j];
            s3 += slab[(size_t)(b+3)*len + j];
        }
        for (; b < nparts; ++b) s0 += slab[(size_t)b*len + j];
        dst[j] = (s0 + s1) + (s2 + s3);
    }
}

// ---------- K3: finalize a1/c1 + w1t  and  asc/csc + wcat[:,0:128] ----------
__global__ __launch_bounds__(512) void k3_finA(const float* __restrict__ XtX, const float* __restrict__ fsum,
    const float* __restrict__ Wu1, const float* __restrict__ g1, const float* __restrict__ b1,
    const float* __restrict__ Wsc, const float* __restrict__ gsc, const float* __restrict__ bsc,
    float invN, float* __restrict__ c1v, ushort* __restrict__ w1t,
    ushort* __restrict__ wcat, float* __restrict__ cscv)
{
    int gw = blockIdx.x*8 + (threadIdx.x >> 6), lane = threadIdx.x & 63;
    if (gw < 64){
        int o = gw; float ai, ci;
        bn_affine_wave(XtX, fsum, Wu1, g1, b1, invN, CIN, CH, o, lane, ai, ci);
        if (lane == 0) c1v[o] = ci;
        for (int k = lane; k < CIN; k += 64) w1t[o*CIN + k] = f2bf(ai*Wu1[k*CH + o]);
    } else if (gw < 320){
        int o = gw - 64; float ai, ci;
        bn_affine_wave(XtX, fsum, Wsc, gsc, bsc, invN, CIN, COUT, o, lane, ai, ci);
        if (lane == 0) cscv[o] = ci;
        for (int k = lane; k < CIN; k += 64) wcat[o*192 + k] = f2bf(ai*Wsc[k*COUT + o]);
    }
}

// ---------- K4: unary1 MFMA -> xbf  +  fused weighted gram64 partials -> slabB ----------
__global__ __launch_bounds__(512) void k4_unary1_gram(const ushort* __restrict__ featbf,
    const ushort* __restrict__ w1t, const float* __restrict__ c1v, const float* __restrict__ cnt,
    ushort* __restrict__ xbf, float* __restrict__ slabB, int N)
{
    __shared__ ushort Xp[64][136];    // plain bf16, [channel][localrow]
    __shared__ ushort Xw[64][136];    // cnt-weighted bf16
    __shared__ float red[8][64];
    int tid = threadIdx.x, bid = blockIdx.x;
    int wave = tid >> 6, lane = tid & 63, l15 = lane & 15, g = lane >> 4;
    const f32x4 z4 = {0.f,0.f,0.f,0.f};
    int row0 = bid*128 + wave*16;
    f32x4 acc[4] = {z4, z4, z4, z4};
    int r = row0 + l15;
    bool ok = r < N;
    #pragma unroll
    for (int s=0;s<4;++s){
        bf16x8 af = {0,0,0,0,0,0,0,0};
        if (ok) af = *(const bf16x8*)(featbf + (size_t)r*CIN + s*32 + g*8);
        #pragma unroll
        for (int nt=0;nt<4;++nt){
            bf16x8 bfr = *(const bf16x8*)(w1t + (size_t)(nt*16+l15)*CIN + s*32 + g*8);
            acc[nt] = __builtin_amdgcn_mfma_f32_16x16x32_bf16(af, bfr, acc[nt], 0,0,0);
        }
    }
    float wq[4];
    #pragma unroll
    for (int q=0;q<4;++q){
        int rr = row0 + g*4 + q;
        wq[q] = (rr < N) ? cnt[rr] : 0.f;
    }
    float ps[4] = {0,0,0,0};
    #pragma unroll
    for (int nt=0;nt<4;++nt){
        int col = nt*16 + l15;
        float cc = c1v[col];
        #pragma unroll
        for (int q=0;q<4;++q){
            int rr = row0 + g*4 + q;
            int lr = wave*16 + g*4 + q;
            float v = (rr < N) ? leakyf(acc[nt][q] + cc) : 0.f;
            ushort b = f2bf(v);
            if (rr < N) xbf[(size_t)rr*CH + col] = b;
            Xp[col][lr] = b;
            float wv = wq[q]*v;
            Xw[col][lr] = f2bf(wv);
            ps[nt] += wv;
        }
    }
    #pragma unroll
    for (int nt=0;nt<4;++nt){
        ps[nt] += __shfl_xor(ps[nt], 16);
        ps[nt] += __shfl_xor(ps[nt], 32);
        if (lane < 16) red[wave][nt*16 + l15] = ps[nt];
    }
    __syncthreads();
    // gram over this block's 128 rows: wave -> (mr = wave>>1, cols (wave&1)*2 + {0,1})
    int mr = wave >> 1, ncb = (wave & 1)*2;
    f32x4 ac2[2] = {z4, z4};
    #pragma unroll
    for (int ks=0;ks<4;++ks){
        bf16x8 af = *(const bf16x8*)&Xw[mr*16 + l15][ks*32 + g*8];
        #pragma unroll
        for (int u=0;u<2;++u){
            bf16x8 bv = *(const bf16x8*)&Xp[(ncb+u)*16 + l15][ks*32 + g*8];
            ac2[u] = __builtin_amdgcn_mfma_f32_16x16x32_bf16(af, bv, ac2[u], 0,0,0);
        }
    }
    float* Gp = slabB + (size_t)bid*4160;
    #pragma unroll
    for (int u=0;u<2;++u)
        #pragma unroll
        for (int q=0;q<4;++q)
            Gp[(mr*16 + g*4 + q)*CH + (ncb+u)*16 + l15] = ac2[u][q];
    if (tid < CH){
        float s = 0.f;
        #pragma unroll
        for (int w8=0;w8<8;++w8) s += red[w8][tid];
        Gp[4096 + tid] = s;
    }
}

// ---------- K6: conv0/conv1 message + stats (round-7 body; folded fin0 prologue:
//             coalesced bn_affine on L1-resident G0 + LDS w0t build) ----------
__global__ __launch_bounds__(512) void conv_msg_mfma(
    const ushort* __restrict__ xbf, const float* __restrict__ qp, const float* __restrict__ sp,
    const int* __restrict__ inds, const ushort* __restrict__ w1s,
    const float* __restrict__ G0, const float* __restrict__ s0,
    const float* __restrict__ W0, const float* __restrict__ gb0, const float* __restrict__ bb0,
    float* __restrict__ mx, float* __restrict__ mn, float* __restrict__ msgpart, int N)
{
    __shared__ unsigned char SM[24576 + 8*12288];
    __shared__ float a0s[64], c0s[64];
    __shared__ ushort w0tl[64*72];   // row stride 72 ushorts = 144B (16B-aligned frag reads)
    int tid = threadIdx.x, bid = blockIdx.x;
    int warp = tid >> 6, lane = tid & 63;
    int l15 = lane & 15, g = lane >> 4;
    // stage w1s swizzled
    for (int ch = tid; ch < 1536; ch += 512){
        int r = ch >> 3, c16 = ch & 7;
        uint4 v = ((const uint4*)w1s)[ch];
        *(uint4*)(SM + r*128 + ((c16*16) ^ ((r&7)<<4))) = v;
    }
    // folded fin0: coalesced affine (8 o's per wave)
    {
        float invNK = 1.0f/((float)N*KNB);
        #pragma unroll
        for (int rr = 0; rr < 8; ++rr){
            int o = warp*8 + rr;
            float ai, ci;
            bn_affine_wave(G0, s0, W0, gb0, bb0, invNK, CH, CH, o, lane, ai, ci);
            if (lane == 0){ a0s[o] = ai; c0s[o] = ci; }
        }
    }
    __syncthreads();
    // build w0t in LDS: w0t[d][c] = a0[d]*W0[c][d]; coalesced W0 reads
    for (int i = tid; i < 4096; i += 512){
        int c = i >> 6, d = i & 63;
        w0tl[d*72 + c] = f2bf(a0s[d]*W0[i]);
    }
    __syncthreads();
    bf16x8 wf[8];
    #pragma unroll
    for (int mt=0;mt<4;++mt)
        #pragma unroll
        for (int s=0;s<2;++s)
            wf[mt*2+s] = *(const bf16x8*)&w0tl[(mt*16+l15)*72 + s*32 + g*8];
    float c0r[16];
    #pragma unroll
    for (int mt=0;mt<4;++mt)
        #pragma unroll
        for (int q=0;q<4;++q)
            c0r[mt*4+q] = c0s[mt*16 + g*4 + q];
    unsigned char* k0base = SM + 24576 + warp*12288;
    unsigned swz = (unsigned)((l15 & 7) << 4);
    float ps[4] = {0,0,0,0}, pss[4] = {0,0,0,0};
    const f32x4 z4 = {0.f,0.f,0.f,0.f};
    __syncthreads();

    for (int n = bid*8 + warp; n < N; n += CONV_GRID*8){
        int ix0 = inds[n*KNB + l15];
        int ix1 = inds[n*KNB + 16 + l15];
        if ((unsigned)ix0 > (unsigned)N) ix0 = N;
        if ((unsigned)ix1 > (unsigned)N) ix1 = N;
        float qx = qp[n*3+0], qy = qp[n*3+1], qz = qp[n*3+2];
        float nbv[2][3];
        if (ix0 < N){ nbv[0][0]=sp[ix0*3]-qx; nbv[0][1]=sp[ix0*3+1]-qy; nbv[0][2]=sp[ix0*3+2]-qz; }
        else        { nbv[0][0]=-qx; nbv[0][1]=-qy; nbv[0][2]=-qz; }
        if (ix1 < N){ nbv[1][0]=sp[ix1*3]-qx; nbv[1][1]=sp[ix1*3+1]-qy; nbv[1][2]=sp[ix1*3+2]-qz; }
        else        { nbv[1][0]=-qx; nbv[1][1]=-qy; nbv[1][2]=-qz; }
        bf16x8 xf0a = *(const bf16x8*)(xbf + (size_t)ix0*CH +      g*8);
        bf16x8 xf0b = *(const bf16x8*)(xbf + (size_t)ix0*CH + 32 + g*8);
        bf16x8 xf1a = *(const bf16x8*)(xbf + (size_t)ix1*CH +      g*8);
        bf16x8 xf1b = *(const bf16x8*)(xbf + (size_t)ix1*CH + 32 + g*8);
        f32x4 acc0[8];
        #pragma unroll
        for (int i=0;i<8;++i) acc0[i] = z4;
        #pragma unroll
        for (int mt=0;mt<4;++mt){
            acc0[mt*2+0] = __builtin_amdgcn_mfma_f32_16x16x32_bf16(wf[mt*2+0], xf0a, acc0[mt*2+0], 0,0,0);
            acc0[mt*2+0] = __builtin_amdgcn_mfma_f32_16x16x32_bf16(wf[mt*2+1], xf0b, acc0[mt*2+0], 0,0,0);
            acc0[mt*2+1] = __builtin_amdgcn_mfma_f32_16x16x32_bf16(wf[mt*2+0], xf1a, acc0[mt*2+1], 0,0,0);
            acc0[mt*2+1] = __builtin_amdgcn_mfma_f32_16x16x32_bf16(wf[mt*2+1], xf1b, acc0[mt*2+1], 0,0,0);
        }
        #pragma unroll
        for (int mt=0;mt<4;++mt){
            #pragma unroll
            for (int ntk=0;ntk<2;++ntk){
                f32x4 a = acc0[mt*2+ntk];
                float v0 = leakyf(a[0] + c0r[mt*4+0]);
                float v1 = leakyf(a[1] + c0r[mt*4+1]);
                float v2 = leakyf(a[2] + c0r[mt*4+2]);
                float v3 = leakyf(a[3] + c0r[mt*4+3]);
                #pragma unroll
                for (int c=0;c<3;++c){
                    float w = nbv[ntk][c];
                    uint2 pk;
                    pk.x = cvtpk(v0*w, v1*w);
                    pk.y = cvtpk(v2*w, v3*w);
                    *(uint2*)(k0base + (c*32 + ntk*16 + l15)*128 + ((unsigned)(mt*32 + g*8) ^ swz)) = pk;
                }
            }
        }
        f32x4 acc1[8];
        #pragma unroll
        for (int i=0;i<8;++i) acc1[i] = z4;
        #pragma unroll
        for (int c=0;c<3;++c){
            #pragma unroll
            for (int ks=0;ks<2;++ks){
                unsigned co = ((unsigned)(ks*64 + g*16)) ^ swz;
                bf16x8 a0f = *(const bf16x8*)(k0base + (c*32 +      l15)*128 + co);
                bf16x8 a1f = *(const bf16x8*)(k0base + (c*32 + 16 + l15)*128 + co);
                #pragma unroll
                for (int nt=0;nt<4;++nt){
                    bf16x8 bfr = *(const bf16x8*)(SM + (c*64 + nt*16 + l15)*128 + co);
                    acc1[0*4+nt] = __builtin_amdgcn_mfma_f32_16x16x32_bf16(a0f, bfr, acc1[0*4+nt], 0,0,0);
                    acc1[1*4+nt] = __builtin_amdgcn_mfma_f32_16x16x32_bf16(a1f, bfr, acc1[1*4+nt], 0,0,0);
                }
            }
        }
        #pragma unroll
        for (int nt=0;nt<4;++nt){
            float vmx = -3.4e38f, vmn = 3.4e38f, s = 0.f, ssq = 0.f;
            #pragma unroll
            for (int mtk=0;mtk<2;++mtk){
                f32x4 a = acc1[mtk*4+nt];
                #pragma unroll
                for (int q=0;q<4;++q){
                    float v = a[q];
                    vmx = fmaxf(vmx, v); vmn = fminf(vmn, v);
                    s += v; ssq += v*v;
                }
            }
            vmx = fmaxf(vmx, __shfl_xor(vmx, 16)); vmn = fminf(vmn, __shfl_xor(vmn, 16));
            s  += __shfl_xor(s, 16);               ssq += __shfl_xor(ssq, 16);
            vmx = fmaxf(vmx, __shfl_xor(vmx, 32)); vmn = fminf(vmn, __shfl_xor(vmn, 32));
            s  += __shfl_xor(s, 32);               ssq += __shfl_xor(ssq, 32);
            if (lane < 16){
                mx[(size_t)n*CH + nt*16 + l15] = vmx;
                mn[(size_t)n*CH + nt*16 + l15] = vmn;
                ps[nt] += s; pss[nt] += ssq;
            }
        }
    }
    __syncthreads();
    float* red = (float*)SM;
    if (lane < 16){
        #pragma unroll
        for (int nt=0;nt<4;++nt){
            red[warp*128 + nt*16 + l15]        = ps[nt];
            red[1024 + warp*128 + nt*16 + l15] = pss[nt];
        }
    }
    __syncthreads();
    if (tid < 64){
        float s = 0.f, ssq = 0.f;
        #pragma unroll
        for (int w8=0;w8<8;++w8){ s += red[w8*128 + tid]; ssq += red[1024 + w8*128 + tid]; }
        msgpart[(size_t)bid*128 + tid]      = s;
        msgpart[(size_t)bid*128 + 64 + tid] = ssq;
    }
}

// ---------- K7: msg aggregation with folded fd1 ----------
__global__ __launch_bounds__(512) void k7_agg(const float* __restrict__ mxb, const float* __restrict__ mnb,
    const float* __restrict__ msgpart, const float* __restrict__ gb1, const float* __restrict__ bb1,
    float* __restrict__ aggb, float* __restrict__ aggpart, int N)
{
    __shared__ float r1[512], r2[512];
    __shared__ float a1ms[64], c1ms[64];
    int tid = threadIdx.x, bid = blockIdx.x;
    {
        int t = tid & 63, seg = tid >> 6;
        float s = 0.f, ss = 0.f;
        for (int r = seg; r < CONV_GRID; r += 8){ s += msgpart[r*128 + t]; ss += msgpart[r*128 + 64 + t]; }
        r1[tid] = s; r2[tid] = ss;
    }
    __syncthreads();
    if (tid < 64){
        float S = 0.f, SS = 0.f;
        #pragma unroll
        for (int k=0;k<8;++k){ S += r1[tid + 64*k]; SS += r2[tid + 64*k]; }
        float invc = 1.0f/((float)N*KNB);
        float m = S*invc, var = SS*invc - m*m;
        float ai = gb1[tid]*rsqrtf(var + BN_EPS);
        a1ms[tid] = ai; c1ms[tid] = bb1[tid] - m*ai;
    }
    __syncthreads();
    int h = tid & 63;
    float ah = a1ms[h], chh = c1ms[h];
    bool useMax = (ah >= 0.f);
    float ps = 0.f, pss = 0.f;
    for (int i = bid*512 + tid; i < N*CH; i += gridDim.x*512){
        float sel = useMax ? mxb[i] : mnb[i];
        float v = leakyf(ah*sel + chh);
        aggb[i] = v; ps += v; pss += v*v;
    }
    __syncthreads();
    r1[tid] = ps; r2[tid] = pss;
    __syncthreads();
    if (tid < 64){
        float S = 0.f, SS = 0.f;
        #pragma unroll
        for (int k=0;k<8;++k){ S += r1[tid + 64*k]; SS += r2[tid + 64*k]; }
        aggpart[(size_t)bid*128 + tid]      = S;
        aggpart[(size_t)bid*128 + 64 + tid] = SS;
    }
}

// ---------- K8: fold fd2 + transform agg -> a2b2 + gram64 partials -> slabC ----------
__global__ __launch_bounds__(512) void k8_gram64t(const float* __restrict__ aggb, const float* __restrict__ aggpart,
    const float* __restrict__ gbc, const float* __restrict__ bbc,
    ushort* __restrict__ a2b2, float* __restrict__ slabC, int N)
{
    __shared__ ushort Xt[64][72];
    __shared__ float red[32][64];
    __shared__ float abncs[64], cbncs[64];
    int tid = threadIdx.x, bid = blockIdx.x;
    int wave = tid >> 6, lane = tid & 63, l15 = lane & 15, g = lane >> 4;
    const f32x4 z4 = {0.f,0.f,0.f,0.f};
    {
        float* r1 = &red[0][0]; float* r2 = r1 + 512;
        int t = tid & 63, seg = tid >> 6;
        float s = 0.f, ss = 0.f;
        for (int r = seg; r < 256; r += 8){ s += aggpart[r*128 + t]; ss += aggpart[r*128 + 64 + t]; }
        r1[tid] = s; r2[tid] = ss;
        __syncthreads();
        if (tid < 64){
            float S = 0.f, SS = 0.f;
            #pragma unroll
            for (int k=0;k<8;++k){ S += r1[tid + 64*k]; SS += r2[tid + 64*k]; }
            float invc = 1.0f/(float)N;
            float m = S*invc, var = SS*invc - m*m;
            float ai = gbc[tid]*rsqrtf(var + BN_EPS);
            abncs[tid] = ai; cbncs[tid] = bbc[tid] - m*ai;
        }
        __syncthreads();
    }
    int wr = wave >> 1, wc = wave & 1;
    f32x4 acc[2] = {z4, z4};
    float pcs[4] = {0,0,0,0};
    int nch = (N + 63) >> 6;
    for (int ch = bid; ch < nch; ch += 256){
        int base = ch << 6;
        __syncthreads();
        #pragma unroll
        for (int ii=0;ii<2;++ii){
            int i = tid + ii*512;
            int r = i >> 4, cq = i & 15;
            int n = base + r;
            float4 v = make_float4(0.f,0.f,0.f,0.f);
            if (n < N){
                v = ((const float4*)aggb)[(size_t)n*16 + cq];
                v.x = leakyf(abncs[cq*4+0]*v.x + cbncs[cq*4+0]);
                v.y = leakyf(abncs[cq*4+1]*v.y + cbncs[cq*4+1]);
                v.z = leakyf(abncs[cq*4+2]*v.z + cbncs[cq*4+2]);
                v.w = leakyf(abncs[cq*4+3]*v.w + cbncs[cq*4+3]);
            }
            uint2 pk; pk.x = cvtpk(v.x, v.y); pk.y = cvtpk(v.z, v.w);
            if (n < N) ((uint2*)a2b2)[(size_t)n*16 + cq] = pk;
            Xt[cq*4+0][r] = (ushort)(pk.x & 0xffff);
            Xt[cq*4+1][r] = (ushort)(pk.x >> 16);
            Xt[cq*4+2][r] = (ushort)(pk.y & 0xffff);
            Xt[cq*4+3][r] = (ushort)(pk.y >> 16);
            pcs[0] += v.x; pcs[1] += v.y; pcs[2] += v.z; pcs[3] += v.w;
        }
        __syncthreads();
        #pragma unroll
        for (int ks=0;ks<2;++ks){
            bf16x8 af = *(const bf16x8*)&Xt[wr*16 + l15][ks*32 + g*8];
            #pragma unroll
            for (int u=0;u<2;++u){
                bf16x8 bv = *(const bf16x8*)&Xt[wc*32 + u*16 + l15][ks*32 + g*8];
                acc[u] = __builtin_amdgcn_mfma_f32_16x16x32_bf16(af, bv, acc[u], 0,0,0);
            }
        }
    }
    float* Gp = slabC + (size_t)bid*4160;
    #pragma unroll
    for (int u=0;u<2;++u)
        #pragma unroll
        for (int q=0;q<4;++q)
            Gp[(wr*16 + g*4 + q)*CH + wc*32 + u*16 + l15] = acc[u][q];
    __syncthreads();
    { int r = tid >> 4, cq = tid & 15;
      #pragma unroll
      for (int j=0;j<4;++j) red[r][cq*4+j] = pcs[j]; }
    __syncthreads();
    if (tid < CH){
        float s = 0.f;
        #pragma unroll
        for (int k=0;k<32;++k) s += red[k][tid];
        Gp[4096 + tid] = s;
    }
}

// ---------- K11: final GEMM [feat|a2] @ [wcat_sc | wu2t]^T -> out (folded fin2 prologue) ----------
__global__ __launch_bounds__(512) void final_mfma_kernel(
    const ushort* __restrict__ featbf, const ushort* __restrict__ a2b2,
    const ushort* __restrict__ wcat,
    const float* __restrict__ G2, const float* __restrict__ s2,
    const float* __restrict__ Wu2, const float* __restrict__ g2, const float* __restrict__ b2,
    const float* __restrict__ cscv, float invN,
    float* __restrict__ out, int N)
{
    __shared__ ushort wu2tl[256*72];   // row stride 72 ushorts = 144B, 16B-aligned frag reads
    __shared__ float a2s[256], ccl[256];
    int tid = threadIdx.x, wave = tid >> 6, lane = tid & 63;
    int l15 = lane & 15, g = lane >> 4;
    // folded fin2: coalesced affine on L2-resident G2 (32 o's per wave)
    for (int rep = 0; rep < 32; ++rep){
        int o = wave*32 + rep;
        float ai, ci;
        bn_affine_wave(G2, s2, Wu2, g2, b2, invN, CH, COUT, o, lane, ai, ci);
        if (lane == 0){ a2s[o] = ai; ccl[o] = cscv[o] + ci; }
    }
    __syncthreads();
    // build scaled Wu2^T in LDS: wu2t[o][k] = a2[o]*Wu2[k][o]; coalesced Wu2 reads
    for (int i = tid; i < 64*256; i += 512){
        int k = i >> 8, o = i & 255;
        wu2tl[o*72 + k] = f2bf(a2s[o]*Wu2[i]);
    }
    __syncthreads();

    int row0 = blockIdx.x*128 + wave*16;
    const f32x4 z4 = {0.f,0.f,0.f,0.f};
    f32x4 acc[16];
    #pragma unroll
    for (int i=0;i<16;++i) acc[i] = z4;
    int r = row0 + l15;
    bool ok = r < N;
    #pragma unroll
    for (int s=0;s<6;++s){
        bf16x8 af = {0,0,0,0,0,0,0,0};
        if (ok){
            const ushort* srcp = (s < 4) ? (featbf + (size_t)r*CIN + s*32 + g*8)
                                         : (a2b2  + (size_t)r*CH + (s-4)*32 + g*8);
            af = *(const bf16x8*)srcp;
        }
        #pragma unroll
        for (int nt=0;nt<16;++nt){
            bf16x8 bfr;
            if (s < 4) bfr = *(const bf16x8*)(wcat + (size_t)(nt*16+l15)*192 + s*32 + g*8);
            else       bfr = *(const bf16x8*)&wu2tl[(nt*16+l15)*72 + (s-4)*32 + g*8];
            acc[nt] = __builtin_amdgcn_mfma_f32_16x16x32_bf16(af, bfr, acc[nt], 0,0,0);
        }
    }
    #pragma unroll
    for (int nt=0;nt<16;++nt){
        float cc = ccl[nt*16 + l15];
        #pragma unroll
        for (int q=0;q<4;++q){
            int rr = row0 + g*4 + q;
            if (rr < N) out[(size_t)rr*COUT + nt*16 + l15] = leakyf(acc[nt][q] + cc);
        }
    }
}

extern "C" void kernel_launch(void* const* d_in, const int* in_sizes, int n_in,
                              void* d_out, int out_size, void* d_ws, size_t ws_size,
                              hipStream_t stream)
{
    const float* feat = (const float*)d_in[0];
    const float* qp   = (const float*)d_in[1];
    const float* sp   = (const float*)d_in[2];
    const int*   inds = (const int*)d_in[3];
    const float* Wu1  = (const float*)d_in[4];
    const float* g1   = (const float*)d_in[5];
    const float* b1   = (const float*)d_in[6];
    const float* W0   = (const float*)d_in[7];
    const float* gb0  = (const float*)d_in[8];
    const float* bb0  = (const float*)d_in[9];
    const float* W1   = (const float*)d_in[10];
    const float* gb1  = (const float*)d_in[11];
    const float* bb1  = (const float*)d_in[12];
    const float* gbc  = (const float*)d_in[13];
    const float* bbc  = (const float*)d_in[14];
    const float* Wu2  = (const float*)d_in[15];
    const float* g2   = (const float*)d_in[16];
    const float* b2   = (const float*)d_in[17];
    const float* Wsc  = (const float*)d_in[18];
    const float* gsc  = (const float*)d_in[19];
    const float* bsc  = (const float*)d_in[20];

    const int N = in_sizes[0] / CIN;           // 20000

    float* ws   = (float*)d_ws;
    float* XtX  = ws;                              // 16384 + 128
    float* fsum = ws + 16384;
    float* G0   = ws + 16512;                      // 4096 + 64
    float* s0   = G0 + 4096;
    float* G2   = ws + 16512 + 4160;               // 4096 + 64
    float* s2   = G2 + 4096;
    float* cnt  = ws + 16512 + 8320;               // N
    float* prm  = cnt + N;                         // 1536
    float* c1v  = prm + 64;
    float* cscv = prm + 768;
    float* msgpart = prm + 1536;                   // CONV_GRID*128
    float* aggpart = msgpart + CONV_GRID*128;      // 256*128
    float* mxb  = aggpart + 256*128;               // N*64
    float* mnb  = mxb + (size_t)N*CH;              // N*64
    float* aggb = mnb + (size_t)N*CH;              // N*64
    ushort* xbf    = (ushort*)(aggb + (size_t)N*CH);
    ushort* featbf = xbf + (size_t)(N+1)*CH;
    ushort* a2b2   = featbf + (size_t)N*CIN;
    ushort* w1s    = a2b2 + (size_t)N*CH;          // 192*64
    ushort* wcat   = w1s + 192*CH;                 // 256*192 (only cols 0..127 used)
    ushort* w1t    = wcat + COUT*192;              // 64*128

    // slab aliasing (stream-order safe):
    float* slabA = mxb;     // 128*16512 <= 2*N*CH   (dead until conv writes mx/mn)
    float* slabB = aggb;    // 157*4160  <= N*CH     (dead until k7 writes aggb)
    float* slabC = mxb;     // 256*4160  <= N*CH     (mxb consumed by k7 before k8)

    const int nTiles = (N + 127)/128;              // 157

    hipMemsetAsync(cnt, 0, (size_t)N*sizeof(float), stream);
    k1_kernel<<<256, 512, 0, stream>>>(feat, inds, W1, N, slabA, featbf, w1s, xbf, cnt);
    reduce_slab<<<(16512 + 255)/256, 256, 0, stream>>>(slabA, 128, 16512, XtX);
    k3_finA<<<40, 512, 0, stream>>>(XtX, fsum, Wu1, g1, b1, Wsc, gsc, bsc, 1.0f/N, c1v, w1t, wcat, cscv);
    k4_unary1_gram<<<nTiles, 512, 0, stream>>>(featbf, w1t, c1v, cnt, xbf, slabB, N);
    reduce_slab<<<(4160 + 255)/256, 256, 0, stream>>>(slabB, nTiles, 4160, G0);
    conv_msg_mfma<<<CONV_GRID, 512, 0, stream>>>(xbf, qp, sp, inds, w1s, G0, s0, W0, gb0, bb0, mxb, mnb, msgpart, N);
    k7_agg<<<256, 512, 0, stream>>>(mxb, mnb, msgpart, gb1, bb1, aggb, aggpart, N);
    k8_gram64t<<<256, 512, 0, stream>>>(aggb, aggpart, gbc, bbc, a2b2, slabC, N);
    reduce_slab<<<(4160 + 255)/256, 256, 0, stream>>>(slabC, 256, 4160, G2);
    final_mfma_kernel<<<nTiles, 512, 0, stream>>>(featbf, a2b2, wcat, G2, s2, Wu2, g2, b2, cscv, 1.0f/N, (float*)d_out, N);
}

// Round 11
// 243.448 us; speedup vs baseline: 1.2567x; 1.2567x over previous
//
#include <hip/hip_runtime.h>

#define KNB 32
#define CIN 128
#define CH 64
#define COUT 256
#define BN_EPS 1e-5f
#define CONV_GRID 256

typedef __attribute__((ext_vector_type(8))) short bf16x8;
typedef __attribute__((ext_vector_type(4))) float f32x4;

static __device__ __forceinline__ float leakyf(float v){ return fmaxf(v, 0.1f*v); }

static __device__ __forceinline__ unsigned short f2bf(float f){
    unsigned u = __float_as_uint(f);
    u += 0x7FFFu + ((u >> 16) & 1u);
    return (unsigned short)(u >> 16);
}
static __device__ __forceinline__ float bf2f(ushort u){ return __uint_as_float(((unsigned)u) << 16); }

static __device__ __forceinline__ unsigned cvtpk(float lo, float hi){
    unsigned r;
    asm("v_cvt_pk_bf16_f32 %0, %1, %2" : "=v"(r) : "v"(lo), "v"(hi));
    return r;
}

// per-wave BN affine from SYMMETRIC Gram/colsum; coalesced: lane indexes the
// contiguous dim of G (pq = w^T G^T w = w^T G w). W[i*M+o] inner reads are
// wave-uniform broadcasts. G must be L1/L2-resident (16KB).
static __device__ __forceinline__ void bn_affine_wave(const float* __restrict__ G, const float* __restrict__ s,
    const float* __restrict__ W, const float* __restrict__ gg, const float* __restrict__ bb,
    float invcnt, int D, int M, int o, int lane, float& ai, float& ci)
{
    float pm = 0.f, pq = 0.f;
    for (int j = lane; j < D; j += 64){
        float wj = W[j*M + o];
        pm += s[j]*wj;
        float t = 0.f;
        for (int i = 0; i < D; ++i) t += G[i*D + j]*W[i*M + o];
        pq += wj*t;
    }
    #pragma unroll
    for (int off = 32; off; off >>= 1){
        pm += __shfl_down(pm, off);
        pq += __shfl_down(pq, off);
    }
    float m  = pm*invcnt;
    float var = pq*invcnt - m*m;
    float a_ = gg[o]*rsqrtf(var + BN_EPS);
    float c_ = bb[o] - m*a_;
    ai = __shfl(a_, 0);
    ci = __shfl(c_, 0);
}

// ---------- K1 split-grid: [0,128) gram128 partials + featbf write ; [128,256) hist+w1s+shadow ----------
__global__ __launch_bounds__(512) void k1_kernel(const float* __restrict__ feat, const int* __restrict__ inds,
    const float* __restrict__ W1, int N,
    float* __restrict__ slabA, ushort* __restrict__ featbf, ushort* __restrict__ w1s,
    ushort* __restrict__ xbf, float* __restrict__ cnt)
{
    __shared__ ushort Xt[128][40];
    __shared__ float red[16][128];
    int tid = threadIdx.x, bid = blockIdx.x;
    if (bid < 128){
        int wave = tid >> 6, lane = tid & 63, l15 = lane & 15, g = lane >> 4;
        int wr = wave >> 1, wc = wave & 1;
        const f32x4 z4 = {0.f,0.f,0.f,0.f};
        f32x4 acc[2][4];
        #pragma unroll
        for (int i=0;i<2;++i)
            #pragma unroll
            for (int j=0;j<4;++j) acc[i][j] = z4;
        float pcs[4] = {0,0,0,0};
        int nch = (N + 31) >> 5;
        for (int ch = bid; ch < nch; ch += 128){
            int base = ch << 5;
            __syncthreads();
            #pragma unroll
            for (int ii=0; ii<2; ++ii){
                int i = tid + ii*512;
                int r = i >> 5, c4 = i & 31;
                int n = base + r;
                float4 v = make_float4(0.f,0.f,0.f,0.f);
                if (n < N) v = ((const float4*)feat)[(size_t)n*32 + c4];
                ushort b0=f2bf(v.x), b1=f2bf(v.y), b2=f2bf(v.z), b3=f2bf(v.w);
                Xt[c4*4+0][r]=b0; Xt[c4*4+1][r]=b1; Xt[c4*4+2][r]=b2; Xt[c4*4+3][r]=b3;
                pcs[0]+=bf2f(b0); pcs[1]+=bf2f(b1); pcs[2]+=bf2f(b2); pcs[3]+=bf2f(b3);
                if (n < N){
                    uint2 pk;
                    pk.x = (unsigned)b0 | ((unsigned)b1 << 16);
                    pk.y = (unsigned)b2 | ((unsigned)b3 << 16);
                    ((uint2*)featbf)[(size_t)n*32 + c4] = pk;
                }
            }
            __syncthreads();
            bf16x8 af[2], bv[4];
            #pragma unroll
            for (int t=0;t<2;++t) af[t] = *(const bf16x8*)&Xt[wr*32 + t*16 + l15][g*8];
            #pragma unroll
            for (int u=0;u<4;++u) bv[u] = *(const bf16x8*)&Xt[wc*64 + u*16 + l15][g*8];
            #pragma unroll
            for (int t=0;t<2;++t)
                #pragma unroll
                for (int u=0;u<4;++u)
                    acc[t][u] = __builtin_amdgcn_mfma_f32_16x16x32_bf16(af[t], bv[u], acc[t][u], 0,0,0);
        }
        float* Gp = slabA + (size_t)bid*16512;
        #pragma unroll
        for (int t=0;t<2;++t)
            #pragma unroll
            for (int u=0;u<4;++u)
                #pragma unroll
                for (int q=0;q<4;++q)
                    Gp[(wr*32 + t*16 + g*4 + q)*CIN + wc*64 + u*16 + l15] = acc[t][u][q];
        __syncthreads();
        { int r16 = tid >> 5, c4 = tid & 31;
          #pragma unroll
          for (int j=0;j<4;++j) red[r16][c4*4+j] = pcs[j]; }
        __syncthreads();
        if (tid < CIN){
            float s = 0.f;
            #pragma unroll
            for (int k=0;k<16;++k) s += red[k][tid];
            Gp[16384 + tid] = s;
        }
    } else {
        int t2 = (bid-128)*512 + tid;
        const int TG = 128*512;
        for (int i = t2; i < N*KNB; i += TG){
            int ix = inds[i];
            if ((unsigned)ix < (unsigned)N) atomicAdd(&cnt[ix], 1.0f);
        }
        if (t2 < 192*CH){
            int r = t2 >> 6, dd = t2 & 63;
            int c = r >> 6, h = r & 63;
            w1s[t2] = f2bf(W1[dd*192 + 3*h + c]);
        }
        if (t2 < CH) xbf[(size_t)N*CH + t2] = 0;
    }
}

// ---------- reduce per-block partial slabs (4 independent accumulator chains) ----------
__global__ __launch_bounds__(256) void reduce_slab(const float* __restrict__ slab, int nparts, int len,
                                                   float* __restrict__ dst)
{
    int j = blockIdx.x*256 + threadIdx.x;
    if (j < len){
        float s0 = 0.f, s1 = 0.f, s2 = 0.f, s3 = 0.f;
        int b = 0;
        for (; b + 4 <= nparts; b += 4){
            s0 += slab[(size_t)(b+0)*len + j];
            s1 += slab[(size_t)(b+1)*len + j];
            s2 += slab[(size_t)(b+2)*len + j];
            s3 += slab[(size_t)(b+3)*len + j];
        }
        for (; b < nparts; ++b) s0 += slab[(size_t)b*len + j];
        dst[j] = (s0 + s1) + (s2 + s3);
    }
}

// ---------- K3: finalize a1/c1 + w1t  and  asc/csc + wcat[:,0:128] ----------
__global__ __launch_bounds__(512) void k3_finA(const float* __restrict__ XtX, const float* __restrict__ fsum,
    const float* __restrict__ Wu1, const float* __restrict__ g1, const float* __restrict__ b1,
    const float* __restrict__ Wsc, const float* __restrict__ gsc, const float* __restrict__ bsc,
    float invN, float* __restrict__ c1v, ushort* __restrict__ w1t,
    ushort* __restrict__ wcat, float* __restrict__ cscv)
{
    int gw = blockIdx.x*8 + (threadIdx.x >> 6), lane = threadIdx.x & 63;
    if (gw < 64){
        int o = gw; float ai, ci;
        bn_affine_wave(XtX, fsum, Wu1, g1, b1, invN, CIN, CH, o, lane, ai, ci);
        if (lane == 0) c1v[o] = ci;
        for (int k = lane; k < CIN; k += 64) w1t[o*CIN + k] = f2bf(ai*Wu1[k*CH + o]);
    } else if (gw < 320){
        int o = gw - 64; float ai, ci;
        bn_affine_wave(XtX, fsum, Wsc, gsc, bsc, invN, CIN, COUT, o, lane, ai, ci);
        if (lane == 0) cscv[o] = ci;
        for (int k = lane; k < CIN; k += 64) wcat[o*192 + k] = f2bf(ai*Wsc[k*COUT + o]);
    }
}

// ---------- K4: unary1 MFMA -> xbf  +  fused weighted gram64 partials -> slabB ----------
__global__ __launch_bounds__(512) void k4_unary1_gram(const ushort* __restrict__ featbf,
    const ushort* __restrict__ w1t, const float* __restrict__ c1v, const float* __restrict__ cnt,
    ushort* __restrict__ xbf, float* __restrict__ slabB, int N)
{
    __shared__ ushort Xp[64][136];    // plain bf16, [channel][localrow]
    __shared__ ushort Xw[64][136];    // cnt-weighted bf16
    __shared__ float red[8][64];
    int tid = threadIdx.x, bid = blockIdx.x;
    int wave = tid >> 6, lane = tid & 63, l15 = lane & 15, g = lane >> 4;
    const f32x4 z4 = {0.f,0.f,0.f,0.f};
    int row0 = bid*128 + wave*16;
    f32x4 acc[4] = {z4, z4, z4, z4};
    int r = row0 + l15;
    bool ok = r < N;
    #pragma unroll
    for (int s=0;s<4;++s){
        bf16x8 af = {0,0,0,0,0,0,0,0};
        if (ok) af = *(const bf16x8*)(featbf + (size_t)r*CIN + s*32 + g*8);
        #pragma unroll
        for (int nt=0;nt<4;++nt){
            bf16x8 bfr = *(const bf16x8*)(w1t + (size_t)(nt*16+l15)*CIN + s*32 + g*8);
            acc[nt] = __builtin_amdgcn_mfma_f32_16x16x32_bf16(af, bfr, acc[nt], 0,0,0);
        }
    }
    float wq[4];
    #pragma unroll
    for (int q=0;q<4;++q){
        int rr = row0 + g*4 + q;
        wq[q] = (rr < N) ? cnt[rr] : 0.f;
    }
    float ps[4] = {0,0,0,0};
    #pragma unroll
    for (int nt=0;nt<4;++nt){
        int col = nt*16 + l15;
        float cc = c1v[col];
        #pragma unroll
        for (int q=0;q<4;++q){
            int rr = row0 + g*4 + q;
            int lr = wave*16 + g*4 + q;
            float v = (rr < N) ? leakyf(acc[nt][q] + cc) : 0.f;
            ushort b = f2bf(v);
            if (rr < N) xbf[(size_t)rr*CH + col] = b;
            Xp[col][lr] = b;
            float wv = wq[q]*v;
            Xw[col][lr] = f2bf(wv);
            ps[nt] += wv;
        }
    }
    #pragma unroll
    for (int nt=0;nt<4;++nt){
        ps[nt] += __shfl_xor(ps[nt], 16);
        ps[nt] += __shfl_xor(ps[nt], 32);
        if (lane < 16) red[wave][nt*16 + l15] = ps[nt];
    }
    __syncthreads();
    // gram over this block's 128 rows: wave -> (mr = wave>>1, cols (wave&1)*2 + {0,1})
    int mr = wave >> 1, ncb = (wave & 1)*2;
    f32x4 ac2[2] = {z4, z4};
    #pragma unroll
    for (int ks=0;ks<4;++ks){
        bf16x8 af = *(const bf16x8*)&Xw[mr*16 + l15][ks*32 + g*8];
        #pragma unroll
        for (int u=0;u<2;++u){
            bf16x8 bv = *(const bf16x8*)&Xp[(ncb+u)*16 + l15][ks*32 + g*8];
            ac2[u] = __builtin_amdgcn_mfma_f32_16x16x32_bf16(af, bv, ac2[u], 0,0,0);
        }
    }
    float* Gp = slabB + (size_t)bid*4160;
    #pragma unroll
    for (int u=0;u<2;++u)
        #pragma unroll
        for (int q=0;q<4;++q)
            Gp[(mr*16 + g*4 + q)*CH + (ncb+u)*16 + l15] = ac2[u][q];
    if (tid < CH){
        float s = 0.f;
        #pragma unroll
        for (int w8=0;w8<8;++w8) s += red[w8][tid];
        Gp[4096 + tid] = s;
    }
}

// ---------- K6: conv0/conv1 message + stats (round-7 body; folded fin0 prologue:
//             coalesced bn_affine on L1-resident G0 + LDS w0t build) ----------
__global__ __launch_bounds__(512) void conv_msg_mfma(
    const ushort* __restrict__ xbf, const float* __restrict__ qp, const float* __restrict__ sp,
    const int* __restrict__ inds, const ushort* __restrict__ w1s,
    const float* __restrict__ G0, const float* __restrict__ s0,
    const float* __restrict__ W0, const float* __restrict__ gb0, const float* __restrict__ bb0,
    float* __restrict__ mx, float* __restrict__ mn, float* __restrict__ msgpart, int N)
{
    __shared__ unsigned char SM[24576 + 8*12288];
    __shared__ float a0s[64], c0s[64];
    __shared__ ushort w0tl[64*72];   // row stride 72 ushorts = 144B (16B-aligned frag reads)
    int tid = threadIdx.x, bid = blockIdx.x;
    int warp = tid >> 6, lane = tid & 63;
    int l15 = lane & 15, g = lane >> 4;
    // stage w1s swizzled
    for (int ch = tid; ch < 1536; ch += 512){
        int r = ch >> 3, c16 = ch & 7;
        uint4 v = ((const uint4*)w1s)[ch];
        *(uint4*)(SM + r*128 + ((c16*16) ^ ((r&7)<<4))) = v;
    }
    // folded fin0: coalesced affine (8 o's per wave) on 16KB L1-resident G0/W0
    {
        float invNK = 1.0f/((float)N*KNB);
        #pragma unroll
        for (int rr = 0; rr < 8; ++rr){
            int o = warp*8 + rr;
            float ai, ci;
            bn_affine_wave(G0, s0, W0, gb0, bb0, invNK, CH, CH, o, lane, ai, ci);
            if (lane == 0){ a0s[o] = ai; c0s[o] = ci; }
        }
    }
    __syncthreads();
    // build w0t in LDS: w0t[d][c] = a0[d]*W0[c][d]; coalesced W0 reads
    for (int i = tid; i < 4096; i += 512){
        int c = i >> 6, d = i & 63;
        w0tl[d*72 + c] = f2bf(a0s[d]*W0[i]);
    }
    __syncthreads();
    bf16x8 wf[8];
    #pragma unroll
    for (int mt=0;mt<4;++mt)
        #pragma unroll
        for (int s=0;s<2;++s)
            wf[mt*2+s] = *(const bf16x8*)&w0tl[(mt*16+l15)*72 + s*32 + g*8];
    float c0r[16];
    #pragma unroll
    for (int mt=0;mt<4;++mt)
        #pragma unroll
        for (int q=0;q<4;++q)
            c0r[mt*4+q] = c0s[mt*16 + g*4 + q];
    unsigned char* k0base = SM + 24576 + warp*12288;
    unsigned swz = (unsigned)((l15 & 7) << 4);
    float ps[4] = {0,0,0,0}, pss[4] = {0,0,0,0};
    const f32x4 z4 = {0.f,0.f,0.f,0.f};
    __syncthreads();

    for (int n = bid*8 + warp; n < N; n += CONV_GRID*8){
        int ix0 = inds[n*KNB + l15];
        int ix1 = inds[n*KNB + 16 + l15];
        if ((unsigned)ix0 > (unsigned)N) ix0 = N;
        if ((unsigned)ix1 > (unsigned)N) ix1 = N;
        float qx = qp[n*3+0], qy = qp[n*3+1], qz = qp[n*3+2];
        float nbv[2][3];
        if (ix0 < N){ nbv[0][0]=sp[ix0*3]-qx; nbv[0][1]=sp[ix0*3+1]-qy; nbv[0][2]=sp[ix0*3+2]-qz; }
        else        { nbv[0][0]=-qx; nbv[0][1]=-qy; nbv[0][2]=-qz; }
        if (ix1 < N){ nbv[1][0]=sp[ix1*3]-qx; nbv[1][1]=sp[ix1*3+1]-qy; nbv[1][2]=sp[ix1*3+2]-qz; }
        else        { nbv[1][0]=-qx; nbv[1][1]=-qy; nbv[1][2]=-qz; }
        bf16x8 xf0a = *(const bf16x8*)(xbf + (size_t)ix0*CH +      g*8);
        bf16x8 xf0b = *(const bf16x8*)(xbf + (size_t)ix0*CH + 32 + g*8);
        bf16x8 xf1a = *(const bf16x8*)(xbf + (size_t)ix1*CH +      g*8);
        bf16x8 xf1b = *(const bf16x8*)(xbf + (size_t)ix1*CH + 32 + g*8);
        f32x4 acc0[8];
        #pragma unroll
        for (int i=0;i<8;++i) acc0[i] = z4;
        #pragma unroll
        for (int mt=0;mt<4;++mt){
            acc0[mt*2+0] = __builtin_amdgcn_mfma_f32_16x16x32_bf16(wf[mt*2+0], xf0a, acc0[mt*2+0], 0,0,0);
            acc0[mt*2+0] = __builtin_amdgcn_mfma_f32_16x16x32_bf16(wf[mt*2+1], xf0b, acc0[mt*2+0], 0,0,0);
            acc0[mt*2+1] = __builtin_amdgcn_mfma_f32_16x16x32_bf16(wf[mt*2+0], xf1a, acc0[mt*2+1], 0,0,0);
            acc0[mt*2+1] = __builtin_amdgcn_mfma_f32_16x16x32_bf16(wf[mt*2+1], xf1b, acc0[mt*2+1], 0,0,0);
        }
        #pragma unroll
        for (int mt=0;mt<4;++mt){
            #pragma unroll
            for (int ntk=0;ntk<2;++ntk){
                f32x4 a = acc0[mt*2+ntk];
                float v0 = leakyf(a[0] + c0r[mt*4+0]);
                float v1 = leakyf(a[1] + c0r[mt*4+1]);
                float v2 = leakyf(a[2] + c0r[mt*4+2]);
                float v3 = leakyf(a[3] + c0r[mt*4+3]);
                #pragma unroll
                for (int c=0;c<3;++c){
                    float w = nbv[ntk][c];
                    uint2 pk;
                    pk.x = cvtpk(v0*w, v1*w);
                    pk.y = cvtpk(v2*w, v3*w);
                    *(uint2*)(k0base + (c*32 + ntk*16 + l15)*128 + ((unsigned)(mt*32 + g*8) ^ swz)) = pk;
                }
            }
        }
        f32x4 acc1[8];
        #pragma unroll
        for (int i=0;i<8;++i) acc1[i] = z4;
        #pragma unroll
        for (int c=0;c<3;++c){
            #pragma unroll
            for (int ks=0;ks<2;++ks){
                unsigned co = ((unsigned)(ks*64 + g*16)) ^ swz;
                bf16x8 a0f = *(const bf16x8*)(k0base + (c*32 +      l15)*128 + co);
                bf16x8 a1f = *(const bf16x8*)(k0base + (c*32 + 16 + l15)*128 + co);
                #pragma unroll
                for (int nt=0;nt<4;++nt){
                    bf16x8 bfr = *(const bf16x8*)(SM + (c*64 + nt*16 + l15)*128 + co);
                    acc1[0*4+nt] = __builtin_amdgcn_mfma_f32_16x16x32_bf16(a0f, bfr, acc1[0*4+nt], 0,0,0);
                    acc1[1*4+nt] = __builtin_amdgcn_mfma_f32_16x16x32_bf16(a1f, bfr, acc1[1*4+nt], 0,0,0);
                }
            }
        }
        #pragma unroll
        for (int nt=0;nt<4;++nt){
            float vmx = -3.4e38f, vmn = 3.4e38f, s = 0.f, ssq = 0.f;
            #pragma unroll
            for (int mtk=0;mtk<2;++mtk){
                f32x4 a = acc1[mtk*4+nt];
                #pragma unroll
                for (int q=0;q<4;++q){
                    float v = a[q];
                    vmx = fmaxf(vmx, v); vmn = fminf(vmn, v);
                    s += v; ssq += v*v;
                }
            }
            vmx = fmaxf(vmx, __shfl_xor(vmx, 16)); vmn = fminf(vmn, __shfl_xor(vmn, 16));
            s  += __shfl_xor(s, 16);               ssq += __shfl_xor(ssq, 16);
            vmx = fmaxf(vmx, __shfl_xor(vmx, 32)); vmn = fminf(vmn, __shfl_xor(vmn, 32));
            s  += __shfl_xor(s, 32);               ssq += __shfl_xor(ssq, 32);
            if (lane < 16){
                mx[(size_t)n*CH + nt*16 + l15] = vmx;
                mn[(size_t)n*CH + nt*16 + l15] = vmn;
                ps[nt] += s; pss[nt] += ssq;
            }
        }
    }
    __syncthreads();
    float* red = (float*)SM;
    if (lane < 16){
        #pragma unroll
        for (int nt=0;nt<4;++nt){
            red[warp*128 + nt*16 + l15]        = ps[nt];
            red[1024 + warp*128 + nt*16 + l15] = pss[nt];
        }
    }
    __syncthreads();
    if (tid < 64){
        float s = 0.f, ssq = 0.f;
        #pragma unroll
        for (int w8=0;w8<8;++w8){ s += red[w8*128 + tid]; ssq += red[1024 + w8*128 + tid]; }
        msgpart[(size_t)bid*128 + tid]      = s;
        msgpart[(size_t)bid*128 + 64 + tid] = ssq;
    }
}

// ---------- K7: msg aggregation with folded fd1 ----------
__global__ __launch_bounds__(512) void k7_agg(const float* __restrict__ mxb, const float* __restrict__ mnb,
    const float* __restrict__ msgpart, const float* __restrict__ gb1, const float* __restrict__ bb1,
    float* __restrict__ aggb, float* __restrict__ aggpart, int N)
{
    __shared__ float r1[512], r2[512];
    __shared__ float a1ms[64], c1ms[64];
    int tid = threadIdx.x, bid = blockIdx.x;
    {
        int t = tid & 63, seg = tid >> 6;
        float s = 0.f, ss = 0.f;
        for (int r = seg; r < CONV_GRID; r += 8){ s += msgpart[r*128 + t]; ss += msgpart[r*128 + 64 + t]; }
        r1[tid] = s; r2[tid] = ss;
    }
    __syncthreads();
    if (tid < 64){
        float S = 0.f, SS = 0.f;
        #pragma unroll
        for (int k=0;k<8;++k){ S += r1[tid + 64*k]; SS += r2[tid + 64*k]; }
        float invc = 1.0f/((float)N*KNB);
        float m = S*invc, var = SS*invc - m*m;
        float ai = gb1[tid]*rsqrtf(var + BN_EPS);
        a1ms[tid] = ai; c1ms[tid] = bb1[tid] - m*ai;
    }
    __syncthreads();
    int h = tid & 63;
    float ah = a1ms[h], chh = c1ms[h];
    bool useMax = (ah >= 0.f);
    float ps = 0.f, pss = 0.f;
    for (int i = bid*512 + tid; i < N*CH; i += gridDim.x*512){
        float sel = useMax ? mxb[i] : mnb[i];
        float v = leakyf(ah*sel + chh);
        aggb[i] = v; ps += v; pss += v*v;
    }
    __syncthreads();
    r1[tid] = ps; r2[tid] = pss;
    __syncthreads();
    if (tid < 64){
        float S = 0.f, SS = 0.f;
        #pragma unroll
        for (int k=0;k<8;++k){ S += r1[tid + 64*k]; SS += r2[tid + 64*k]; }
        aggpart[(size_t)bid*128 + tid]      = S;
        aggpart[(size_t)bid*128 + 64 + tid] = SS;
    }
}

// ---------- K8: fold fd2 + transform agg -> a2b2 + gram64 partials -> slabC ----------
__global__ __launch_bounds__(512) void k8_gram64t(const float* __restrict__ aggb, const float* __restrict__ aggpart,
    const float* __restrict__ gbc, const float* __restrict__ bbc,
    ushort* __restrict__ a2b2, float* __restrict__ slabC, int N)
{
    __shared__ ushort Xt[64][72];
    __shared__ float red[32][64];
    __shared__ float abncs[64], cbncs[64];
    int tid = threadIdx.x, bid = blockIdx.x;
    int wave = tid >> 6, lane = tid & 63, l15 = lane & 15, g = lane >> 4;
    const f32x4 z4 = {0.f,0.f,0.f,0.f};
    {
        float* r1 = &red[0][0]; float* r2 = r1 + 512;
        int t = tid & 63, seg = tid >> 6;
        float s = 0.f, ss = 0.f;
        for (int r = seg; r < 256; r += 8){ s += aggpart[r*128 + t]; ss += aggpart[r*128 + 64 + t]; }
        r1[tid] = s; r2[tid] = ss;
        __syncthreads();
        if (tid < 64){
            float S = 0.f, SS = 0.f;
            #pragma unroll
            for (int k=0;k<8;++k){ S += r1[tid + 64*k]; SS += r2[tid + 64*k]; }
            float invc = 1.0f/(float)N;
            float m = S*invc, var = SS*invc - m*m;
            float ai = gbc[tid]*rsqrtf(var + BN_EPS);
            abncs[tid] = ai; cbncs[tid] = bbc[tid] - m*ai;
        }
        __syncthreads();
    }
    int wr = wave >> 1, wc = wave & 1;
    f32x4 acc[2] = {z4, z4};
    float pcs[4] = {0,0,0,0};
    int nch = (N + 63) >> 6;
    for (int ch = bid; ch < nch; ch += 256){
        int base = ch << 6;
        __syncthreads();
        #pragma unroll
        for (int ii=0;ii<2;++ii){
            int i = tid + ii*512;
            int r = i >> 4, cq = i & 15;
            int n = base + r;
            float4 v = make_float4(0.f,0.f,0.f,0.f);
            if (n < N){
                v = ((const float4*)aggb)[(size_t)n*16 + cq];
                v.x = leakyf(abncs[cq*4+0]*v.x + cbncs[cq*4+0]);
                v.y = leakyf(abncs[cq*4+1]*v.y + cbncs[cq*4+1]);
                v.z = leakyf(abncs[cq*4+2]*v.z + cbncs[cq*4+2]);
                v.w = leakyf(abncs[cq*4+3]*v.w + cbncs[cq*4+3]);
            }
            uint2 pk; pk.x = cvtpk(v.x, v.y); pk.y = cvtpk(v.z, v.w);
            if (n < N) ((uint2*)a2b2)[(size_t)n*16 + cq] = pk;
            Xt[cq*4+0][r] = (ushort)(pk.x & 0xffff);
            Xt[cq*4+1][r] = (ushort)(pk.x >> 16);
            Xt[cq*4+2][r] = (ushort)(pk.y & 0xffff);
            Xt[cq*4+3][r] = (ushort)(pk.y >> 16);
            pcs[0] += v.x; pcs[1] += v.y; pcs[2] += v.z; pcs[3] += v.w;
        }
        __syncthreads();
        #pragma unroll
        for (int ks=0;ks<2;++ks){
            bf16x8 af = *(const bf16x8*)&Xt[wr*16 + l15][ks*32 + g*8];
            #pragma unroll
            for (int u=0;u<2;++u){
                bf16x8 bv = *(const bf16x8*)&Xt[wc*32 + u*16 + l15][ks*32 + g*8];
                acc[u] = __builtin_amdgcn_mfma_f32_16x16x32_bf16(af, bv, acc[u], 0,0,0);
            }
        }
    }
    float* Gp = slabC + (size_t)bid*4160;
    #pragma unroll
    for (int u=0;u<2;++u)
        #pragma unroll
        for (int q=0;q<4;++q)
            Gp[(wr*16 + g*4 + q)*CH + wc*32 + u*16 + l15] = acc[u][q];
    __syncthreads();
    { int r = tid >> 4, cq = tid & 15;
      #pragma unroll
      for (int j=0;j<4;++j) red[r][cq*4+j] = pcs[j]; }
    __syncthreads();
    if (tid < CH){
        float s = 0.f;
        #pragma unroll
        for (int k=0;k<32;++k) s += red[k][tid];
        Gp[4096 + tid] = s;
    }
}

// ---------- K10: finalize unary2 BN + wcat[:,128:192] + ccomb from reduced G2 ----------
__global__ __launch_bounds__(512) void k10_fin2(const float* __restrict__ G2, const float* __restrict__ s2,
    const float* __restrict__ Wu2, const float* __restrict__ g2, const float* __restrict__ b2,
    const float* __restrict__ cscv, float invN, ushort* __restrict__ wcat, float* __restrict__ ccomb)
{
    int gw = blockIdx.x*8 + (threadIdx.x >> 6), lane = threadIdx.x & 63;
    if (gw < 256){
        float ai, ci;
        bn_affine_wave(G2, s2, Wu2, g2, b2, invN, CH, COUT, gw, lane, ai, ci);
        wcat[gw*192 + 128 + lane] = f2bf(ai*Wu2[lane*COUT + gw]);
        if (lane == 0) ccomb[gw] = cscv[gw] + ci;
    }
}

// ---------- K11: final GEMM [feat|a2] @ wcat^T -> out ----------
__global__ __launch_bounds__(512) void final_mfma_kernel(
    const ushort* __restrict__ featbf, const ushort* __restrict__ a2b2,
    const ushort* __restrict__ wcat, const float* __restrict__ ccomb,
    float* __restrict__ out, int N)
{
    int tid = threadIdx.x, wave = tid >> 6, lane = tid & 63;
    int l15 = lane & 15, g = lane >> 4;
    int row0 = blockIdx.x*128 + wave*16;
    const f32x4 z4 = {0.f,0.f,0.f,0.f};
    f32x4 acc[16];
    #pragma unroll
    for (int i=0;i<16;++i) acc[i] = z4;
    int r = row0 + l15;
    bool ok = r < N;
    #pragma unroll
    for (int s=0;s<6;++s){
        bf16x8 af = {0,0,0,0,0,0,0,0};
        if (ok){
            const ushort* srcp = (s < 4) ? (featbf + (size_t)r*CIN + s*32 + g*8)
                                         : (a2b2  + (size_t)r*CH + (s-4)*32 + g*8);
            af = *(const bf16x8*)srcp;
        }
        #pragma unroll
        for (int nt=0;nt<16;++nt){
            bf16x8 bfr = *(const bf16x8*)(wcat + (size_t)(nt*16+l15)*192 + s*32 + g*8);
            acc[nt] = __builtin_amdgcn_mfma_f32_16x16x32_bf16(af, bfr, acc[nt], 0,0,0);
        }
    }
    #pragma unroll
    for (int nt=0;nt<16;++nt){
        float cc = ccomb[nt*16 + l15];
        #pragma unroll
        for (int q=0;q<4;++q){
            int rr = row0 + g*4 + q;
            if (rr < N) out[(size_t)rr*COUT + nt*16 + l15] = leakyf(acc[nt][q] + cc);
        }
    }
}

extern "C" void kernel_launch(void* const* d_in, const int* in_sizes, int n_in,
                              void* d_out, int out_size, void* d_ws, size_t ws_size,
                              hipStream_t stream)
{
    const float* feat = (const float*)d_in[0];
    const float* qp   = (const float*)d_in[1];
    const float* sp   = (const float*)d_in[2];
    const int*   inds = (const int*)d_in[3];
    const float* Wu1  = (const float*)d_in[4];
    const float* g1   = (const float*)d_in[5];
    const float* b1   = (const float*)d_in[6];
    const float* W0   = (const float*)d_in[7];
    const float* gb0  = (const float*)d_in[8];
    const float* bb0  = (const float*)d_in[9];
    const float* W1   = (const float*)d_in[10];
    const float* gb1  = (const float*)d_in[11];
    const float* bb1  = (const float*)d_in[12];
    const float* gbc  = (const float*)d_in[13];
    const float* bbc  = (const float*)d_in[14];
    const float* Wu2  = (const float*)d_in[15];
    const float* g2   = (const float*)d_in[16];
    const float* b2   = (const float*)d_in[17];
    const float* Wsc  = (const float*)d_in[18];
    const float* gsc  = (const float*)d_in[19];
    const float* bsc  = (const float*)d_in[20];

    const int N = in_sizes[0] / CIN;           // 20000

    float* ws   = (float*)d_ws;
    float* XtX  = ws;                              // 16384 + 128
    float* fsum = ws + 16384;
    float* G0   = ws + 16512;                      // 4096 + 64
    float* s0   = G0 + 4096;
    float* G2   = ws + 16512 + 4160;               // 4096 + 64
    float* s2   = G2 + 4096;
    float* cnt  = ws + 16512 + 8320;               // N
    float* prm  = cnt + N;                         // 1536
    float* c1v  = prm + 64;
    float* cscv = prm + 768;
    float* msgpart = prm + 1536;                   // CONV_GRID*128
    float* aggpart = msgpart + CONV_GRID*128;      // 256*128
    float* mxb  = aggpart + 256*128;               // N*64
    float* mnb  = mxb + (size_t)N*CH;              // N*64
    float* aggb = mnb + (size_t)N*CH;              // N*64
    ushort* xbf    = (ushort*)(aggb + (size_t)N*CH);
    ushort* featbf = xbf + (size_t)(N+1)*CH;
    ushort* a2b2   = featbf + (size_t)N*CIN;
    ushort* w1s    = a2b2 + (size_t)N*CH;          // 192*64
    ushort* wcat   = w1s + 192*CH;                 // 256*192
    ushort* w1t    = wcat + COUT*192;              // 64*128
    float*  ccomb  = (float*)(w1t + CH*CIN);       // 256

    // slab aliasing (stream-order safe):
    float* slabA = mxb;     // 128*16512 <= 2*N*CH   (dead until conv writes mx/mn)
    float* slabB = aggb;    // 157*4160  <= N*CH     (dead until k7 writes aggb)
    float* slabC = mxb;     // 256*4160  <= N*CH     (mxb consumed by k7 before k8)

    const int nTiles = (N + 127)/128;              // 157

    hipMemsetAsync(cnt, 0, (size_t)N*sizeof(float), stream);
    k1_kernel<<<256, 512, 0, stream>>>(feat, inds, W1, N, slabA, featbf, w1s, xbf, cnt);
    reduce_slab<<<(16512 + 255)/256, 256, 0, stream>>>(slabA, 128, 16512, XtX);
    k3_finA<<<40, 512, 0, stream>>>(XtX, fsum, Wu1, g1, b1, Wsc, gsc, bsc, 1.0f/N, c1v, w1t, wcat, cscv);
    k4_unary1_gram<<<nTiles, 512, 0, stream>>>(featbf, w1t, c1v, cnt, xbf, slabB, N);
    reduce_slab<<<(4160 + 255)/256, 256, 0, stream>>>(slabB, nTiles, 4160, G0);
    conv_msg_mfma<<<CONV_GRID, 512, 0, stream>>>(xbf, qp, sp, inds, w1s, G0, s0, W0, gb0, bb0, mxb, mnb, msgpart, N);
    k7_agg<<<256, 512, 0, stream>>>(mxb, mnb, msgpart, gb1, bb1, aggb, aggpart, N);
    k8_gram64t<<<256, 512, 0, stream>>>(aggb, aggpart, gbc, bbc, a2b2, slabC, N);
    reduce_slab<<<(4160 + 255)/256, 256, 0, stream>>>(slabC, 256, 4160, G2);
    k10_fin2<<<32, 512, 0, stream>>>(G2, s2, Wu2, g2, b2, cscv, 1.0f/N, wcat, ccomb);
    final_mfma_kernel<<<nTiles, 512, 0, stream>>>(featbf, a2b2, wcat, ccomb, (float*)d_out, N);
}

// Round 12
// 232.746 us; speedup vs baseline: 1.3145x; 1.0460x over previous
//
#include <hip/hip_runtime.h>

#define KNB 32
#define CIN 128
#define CH 64
#define COUT 256
#define BN_EPS 1e-5f
#define CONV_GRID 256

typedef __attribute__((ext_vector_type(8))) short bf16x8;
typedef __attribute__((ext_vector_type(4))) float f32x4;

static __device__ __forceinline__ float leakyf(float v){ return fmaxf(v, 0.1f*v); }

static __device__ __forceinline__ unsigned short f2bf(float f){
    unsigned u = __float_as_uint(f);
    u += 0x7FFFu + ((u >> 16) & 1u);
    return (unsigned short)(u >> 16);
}
static __device__ __forceinline__ float bf2f(ushort u){ return __uint_as_float(((unsigned)u) << 16); }

static __device__ __forceinline__ unsigned cvtpk(float lo, float hi){
    unsigned r;
    asm("v_cvt_pk_bf16_f32 %0, %1, %2" : "=v"(r) : "v"(lo), "v"(hi));
    return r;
}

// per-wave BN affine from SYMMETRIC Gram/colsum; coalesced: lane indexes the
// contiguous dim of G (pq = w^T G^T w = w^T G w). W[i*M+o] inner reads are
// wave-uniform broadcasts. G must be L1/L2-resident (16KB).
static __device__ __forceinline__ void bn_affine_wave(const float* __restrict__ G, const float* __restrict__ s,
    const float* __restrict__ W, const float* __restrict__ gg, const float* __restrict__ bb,
    float invcnt, int D, int M, int o, int lane, float& ai, float& ci)
{
    float pm = 0.f, pq = 0.f;
    for (int j = lane; j < D; j += 64){
        float wj = W[j*M + o];
        pm += s[j]*wj;
        float t = 0.f;
        for (int i = 0; i < D; ++i) t += G[i*D + j]*W[i*M + o];
        pq += wj*t;
    }
    #pragma unroll
    for (int off = 32; off; off >>= 1){
        pm += __shfl_down(pm, off);
        pq += __shfl_down(pq, off);
    }
    float m  = pm*invcnt;
    float var = pq*invcnt - m*m;
    float a_ = gg[o]*rsqrtf(var + BN_EPS);
    float c_ = bb[o] - m*a_;
    ai = __shfl(a_, 0);
    ci = __shfl(c_, 0);
}

// ---------- K1 split-grid: [0,128) gram128 partials + featbf write ; [128,256) hist+w1s+shadow ----------
__global__ __launch_bounds__(512) void k1_kernel(const float* __restrict__ feat, const int* __restrict__ inds,
    const float* __restrict__ W1, int N,
    float* __restrict__ slabA, ushort* __restrict__ featbf, ushort* __restrict__ w1s,
    ushort* __restrict__ xbf, float* __restrict__ cnt)
{
    __shared__ ushort Xt[128][40];
    __shared__ float red[16][128];
    int tid = threadIdx.x, bid = blockIdx.x;
    if (bid < 128){
        int wave = tid >> 6, lane = tid & 63, l15 = lane & 15, g = lane >> 4;
        int wr = wave >> 1, wc = wave & 1;
        const f32x4 z4 = {0.f,0.f,0.f,0.f};
        f32x4 acc[2][4];
        #pragma unroll
        for (int i=0;i<2;++i)
            #pragma unroll
            for (int j=0;j<4;++j) acc[i][j] = z4;
        float pcs[4] = {0,0,0,0};
        int nch = (N + 31) >> 5;
        for (int ch = bid; ch < nch; ch += 128){
            int base = ch << 5;
            __syncthreads();
            #pragma unroll
            for (int ii=0; ii<2; ++ii){
                int i = tid + ii*512;
                int r = i >> 5, c4 = i & 31;
                int n = base + r;
                float4 v = make_float4(0.f,0.f,0.f,0.f);
                if (n < N) v = ((const float4*)feat)[(size_t)n*32 + c4];
                ushort b0=f2bf(v.x), b1=f2bf(v.y), b2=f2bf(v.z), b3=f2bf(v.w);
                Xt[c4*4+0][r]=b0; Xt[c4*4+1][r]=b1; Xt[c4*4+2][r]=b2; Xt[c4*4+3][r]=b3;
                pcs[0]+=bf2f(b0); pcs[1]+=bf2f(b1); pcs[2]+=bf2f(b2); pcs[3]+=bf2f(b3);
                if (n < N){
                    uint2 pk;
                    pk.x = (unsigned)b0 | ((unsigned)b1 << 16);
                    pk.y = (unsigned)b2 | ((unsigned)b3 << 16);
                    ((uint2*)featbf)[(size_t)n*32 + c4] = pk;
                }
            }
            __syncthreads();
            bf16x8 af[2], bv[4];
            #pragma unroll
            for (int t=0;t<2;++t) af[t] = *(const bf16x8*)&Xt[wr*32 + t*16 + l15][g*8];
            #pragma unroll
            for (int u=0;u<4;++u) bv[u] = *(const bf16x8*)&Xt[wc*64 + u*16 + l15][g*8];
            #pragma unroll
            for (int t=0;t<2;++t)
                #pragma unroll
                for (int u=0;u<4;++u)
                    acc[t][u] = __builtin_amdgcn_mfma_f32_16x16x32_bf16(af[t], bv[u], acc[t][u], 0,0,0);
        }
        float* Gp = slabA + (size_t)bid*16512;
        #pragma unroll
        for (int t=0;t<2;++t)
            #pragma unroll
            for (int u=0;u<4;++u)
                #pragma unroll
                for (int q=0;q<4;++q)
                    Gp[(wr*32 + t*16 + g*4 + q)*CIN + wc*64 + u*16 + l15] = acc[t][u][q];
        __syncthreads();
        { int r16 = tid >> 5, c4 = tid & 31;
          #pragma unroll
          for (int j=0;j<4;++j) red[r16][c4*4+j] = pcs[j]; }
        __syncthreads();
        if (tid < CIN){
            float s = 0.f;
            #pragma unroll
            for (int k=0;k<16;++k) s += red[k][tid];
            Gp[16384 + tid] = s;
        }
    } else {
        int t2 = (bid-128)*512 + tid;
        const int TG = 128*512;
        for (int i = t2; i < N*KNB; i += TG){
            int ix = inds[i];
            if ((unsigned)ix < (unsigned)N) atomicAdd(&cnt[ix], 1.0f);
        }
        if (t2 < 192*CH){
            int r = t2 >> 6, dd = t2 & 63;
            int c = r >> 6, h = r & 63;
            w1s[t2] = f2bf(W1[dd*192 + 3*h + c]);
        }
        if (t2 < CH) xbf[(size_t)N*CH + t2] = 0;
    }
}

// ---------- reduce per-block partial slabs (4 independent accumulator chains) ----------
__global__ __launch_bounds__(256) void reduce_slab(const float* __restrict__ slab, int nparts, int len,
                                                   float* __restrict__ dst)
{
    int j = blockIdx.x*256 + threadIdx.x;
    if (j < len){
        float s0 = 0.f, s1 = 0.f, s2 = 0.f, s3 = 0.f;
        int b = 0;
        for (; b + 4 <= nparts; b += 4){
            s0 += slab[(size_t)(b+0)*len + j];
            s1 += slab[(size_t)(b+1)*len + j];
            s2 += slab[(size_t)(b+2)*len + j];
            s3 += slab[(size_t)(b+3)*len + j];
        }
        for (; b < nparts; ++b) s0 += slab[(size_t)b*len + j];
        dst[j] = (s0 + s1) + (s2 + s3);
    }
}

// ---------- K3: finalize a1/c1 + w1t  and  asc/csc + wcat[:,0:128] ----------
__global__ __launch_bounds__(512) void k3_finA(const float* __restrict__ XtX, const float* __restrict__ fsum,
    const float* __restrict__ Wu1, const float* __restrict__ g1, const float* __restrict__ b1,
    const float* __restrict__ Wsc, const float* __restrict__ gsc, const float* __restrict__ bsc,
    float invN, float* __restrict__ c1v, ushort* __restrict__ w1t,
    ushort* __restrict__ wcat, float* __restrict__ cscv)
{
    int gw = blockIdx.x*8 + (threadIdx.x >> 6), lane = threadIdx.x & 63;
    if (gw < 64){
        int o = gw; float ai, ci;
        bn_affine_wave(XtX, fsum, Wu1, g1, b1, invN, CIN, CH, o, lane, ai, ci);
        if (lane == 0) c1v[o] = ci;
        for (int k = lane; k < CIN; k += 64) w1t[o*CIN + k] = f2bf(ai*Wu1[k*CH + o]);
    } else if (gw < 320){
        int o = gw - 64; float ai, ci;
        bn_affine_wave(XtX, fsum, Wsc, gsc, bsc, invN, CIN, COUT, o, lane, ai, ci);
        if (lane == 0) cscv[o] = ci;
        for (int k = lane; k < CIN; k += 64) wcat[o*192 + k] = f2bf(ai*Wsc[k*COUT + o]);
    }
}

// ---------- K4: unary1 MFMA -> xbf  +  fused weighted gram64 partials -> slabB ----------
__global__ __launch_bounds__(512) void k4_unary1_gram(const ushort* __restrict__ featbf,
    const ushort* __restrict__ w1t, const float* __restrict__ c1v, const float* __restrict__ cnt,
    ushort* __restrict__ xbf, float* __restrict__ slabB, int N)
{
    __shared__ ushort Xp[64][136];    // plain bf16, [channel][localrow]
    __shared__ ushort Xw[64][136];    // cnt-weighted bf16
    __shared__ float red[8][64];
    int tid = threadIdx.x, bid = blockIdx.x;
    int wave = tid >> 6, lane = tid & 63, l15 = lane & 15, g = lane >> 4;
    const f32x4 z4 = {0.f,0.f,0.f,0.f};
    int row0 = bid*128 + wave*16;
    f32x4 acc[4] = {z4, z4, z4, z4};
    int r = row0 + l15;
    bool ok = r < N;
    #pragma unroll
    for (int s=0;s<4;++s){
        bf16x8 af = {0,0,0,0,0,0,0,0};
        if (ok) af = *(const bf16x8*)(featbf + (size_t)r*CIN + s*32 + g*8);
        #pragma unroll
        for (int nt=0;nt<4;++nt){
            bf16x8 bfr = *(const bf16x8*)(w1t + (size_t)(nt*16+l15)*CIN + s*32 + g*8);
            acc[nt] = __builtin_amdgcn_mfma_f32_16x16x32_bf16(af, bfr, acc[nt], 0,0,0);
        }
    }
    float wq[4];
    #pragma unroll
    for (int q=0;q<4;++q){
        int rr = row0 + g*4 + q;
        wq[q] = (rr < N) ? cnt[rr] : 0.f;
    }
    float ps[4] = {0,0,0,0};
    #pragma unroll
    for (int nt=0;nt<4;++nt){
        int col = nt*16 + l15;
        float cc = c1v[col];
        #pragma unroll
        for (int q=0;q<4;++q){
            int rr = row0 + g*4 + q;
            int lr = wave*16 + g*4 + q;
            float v = (rr < N) ? leakyf(acc[nt][q] + cc) : 0.f;
            ushort b = f2bf(v);
            if (rr < N) xbf[(size_t)rr*CH + col] = b;
            Xp[col][lr] = b;
            float wv = wq[q]*v;
            Xw[col][lr] = f2bf(wv);
            ps[nt] += wv;
        }
    }
    #pragma unroll
    for (int nt=0;nt<4;++nt){
        ps[nt] += __shfl_xor(ps[nt], 16);
        ps[nt] += __shfl_xor(ps[nt], 32);
        if (lane < 16) red[wave][nt*16 + l15] = ps[nt];
    }
    __syncthreads();
    // gram over this block's 128 rows: wave -> (mr = wave>>1, cols (wave&1)*2 + {0,1})
    int mr = wave >> 1, ncb = (wave & 1)*2;
    f32x4 ac2[2] = {z4, z4};
    #pragma unroll
    for (int ks=0;ks<4;++ks){
        bf16x8 af = *(const bf16x8*)&Xw[mr*16 + l15][ks*32 + g*8];
        #pragma unroll
        for (int u=0;u<2;++u){
            bf16x8 bv = *(const bf16x8*)&Xp[(ncb+u)*16 + l15][ks*32 + g*8];
            ac2[u] = __builtin_amdgcn_mfma_f32_16x16x32_bf16(af, bv, ac2[u], 0,0,0);
        }
    }
    float* Gp = slabB + (size_t)bid*4160;
    #pragma unroll
    for (int u=0;u<2;++u)
        #pragma unroll
        for (int q=0;q<4;++q)
            Gp[(mr*16 + g*4 + q)*CH + (ncb+u)*16 + l15] = ac2[u][q];
    if (tid < CH){
        float s = 0.f;
        #pragma unroll
        for (int w8=0;w8<8;++w8) s += red[w8][tid];
        Gp[4096 + tid] = s;
    }
}

// ---------- K5: finalize a0/c0 + w0t from reduced G0 (8 blocks) ----------
__global__ __launch_bounds__(512) void k5_fin0(const float* __restrict__ G0, const float* __restrict__ s0,
    const float* __restrict__ W0, const float* __restrict__ gb0, const float* __restrict__ bb0,
    float invNK, float* __restrict__ c0p, ushort* __restrict__ w0t)
{
    int gw = blockIdx.x*8 + (threadIdx.x >> 6), lane = threadIdx.x & 63;
    if (gw < 64){
        float ai, ci;
        bn_affine_wave(G0, s0, W0, gb0, bb0, invNK, CH, CH, gw, lane, ai, ci);
        if (lane == 0) c0p[gw] = ci;
        w0t[gw*CH + lane] = f2bf(ai*W0[lane*CH + gw]);
    }
}

// ---------- K6: conv0/conv1 message + stats (round-7 proven body) ----------
__global__ __launch_bounds__(512) void conv_msg_mfma(
    const ushort* __restrict__ xbf, const float* __restrict__ qp, const float* __restrict__ sp,
    const int* __restrict__ inds, const ushort* __restrict__ w0t, const ushort* __restrict__ w1s,
    const float* __restrict__ c0p,
    float* __restrict__ mx, float* __restrict__ mn, float* __restrict__ msgpart, int N)
{
    __shared__ unsigned char SM[24576 + 8*12288];
    int tid = threadIdx.x, bid = blockIdx.x;
    int warp = tid >> 6, lane = tid & 63;
    int l15 = lane & 15, g = lane >> 4;
    // stage w1s swizzled
    for (int ch = tid; ch < 1536; ch += 512){
        int r = ch >> 3, c16 = ch & 7;
        uint4 v = ((const uint4*)w1s)[ch];
        *(uint4*)(SM + r*128 + ((c16*16) ^ ((r&7)<<4))) = v;
    }
    bf16x8 wf[8];
    #pragma unroll
    for (int mt=0;mt<4;++mt)
        #pragma unroll
        for (int s=0;s<2;++s)
            wf[mt*2+s] = *(const bf16x8*)(w0t + (mt*16+l15)*CH + s*32 + g*8);
    float c0r[16];
    #pragma unroll
    for (int mt=0;mt<4;++mt)
        #pragma unroll
        for (int q=0;q<4;++q)
            c0r[mt*4+q] = c0p[mt*16 + g*4 + q];
    unsigned char* k0base = SM + 24576 + warp*12288;
    unsigned swz = (unsigned)((l15 & 7) << 4);
    float ps[4] = {0,0,0,0}, pss[4] = {0,0,0,0};
    const f32x4 z4 = {0.f,0.f,0.f,0.f};
    __syncthreads();

    for (int n = bid*8 + warp; n < N; n += CONV_GRID*8){
        int ix0 = inds[n*KNB + l15];
        int ix1 = inds[n*KNB + 16 + l15];
        if ((unsigned)ix0 > (unsigned)N) ix0 = N;
        if ((unsigned)ix1 > (unsigned)N) ix1 = N;
        float qx = qp[n*3+0], qy = qp[n*3+1], qz = qp[n*3+2];
        float nbv[2][3];
        if (ix0 < N){ nbv[0][0]=sp[ix0*3]-qx; nbv[0][1]=sp[ix0*3+1]-qy; nbv[0][2]=sp[ix0*3+2]-qz; }
        else        { nbv[0][0]=-qx; nbv[0][1]=-qy; nbv[0][2]=-qz; }
        if (ix1 < N){ nbv[1][0]=sp[ix1*3]-qx; nbv[1][1]=sp[ix1*3+1]-qy; nbv[1][2]=sp[ix1*3+2]-qz; }
        else        { nbv[1][0]=-qx; nbv[1][1]=-qy; nbv[1][2]=-qz; }
        bf16x8 xf0a = *(const bf16x8*)(xbf + (size_t)ix0*CH +      g*8);
        bf16x8 xf0b = *(const bf16x8*)(xbf + (size_t)ix0*CH + 32 + g*8);
        bf16x8 xf1a = *(const bf16x8*)(xbf + (size_t)ix1*CH +      g*8);
        bf16x8 xf1b = *(const bf16x8*)(xbf + (size_t)ix1*CH + 32 + g*8);
        f32x4 acc0[8];
        #pragma unroll
        for (int i=0;i<8;++i) acc0[i] = z4;
        #pragma unroll
        for (int mt=0;mt<4;++mt){
            acc0[mt*2+0] = __builtin_amdgcn_mfma_f32_16x16x32_bf16(wf[mt*2+0], xf0a, acc0[mt*2+0], 0,0,0);
            acc0[mt*2+0] = __builtin_amdgcn_mfma_f32_16x16x32_bf16(wf[mt*2+1], xf0b, acc0[mt*2+0], 0,0,0);
            acc0[mt*2+1] = __builtin_amdgcn_mfma_f32_16x16x32_bf16(wf[mt*2+0], xf1a, acc0[mt*2+1], 0,0,0);
            acc0[mt*2+1] = __builtin_amdgcn_mfma_f32_16x16x32_bf16(wf[mt*2+1], xf1b, acc0[mt*2+1], 0,0,0);
        }
        #pragma unroll
        for (int mt=0;mt<4;++mt){
            #pragma unroll
            for (int ntk=0;ntk<2;++ntk){
                f32x4 a = acc0[mt*2+ntk];
                float v0 = leakyf(a[0] + c0r[mt*4+0]);
                float v1 = leakyf(a[1] + c0r[mt*4+1]);
                float v2 = leakyf(a[2] + c0r[mt*4+2]);
                float v3 = leakyf(a[3] + c0r[mt*4+3]);
                #pragma unroll
                for (int c=0;c<3;++c){
                    float w = nbv[ntk][c];
                    uint2 pk;
                    pk.x = cvtpk(v0*w, v1*w);
                    pk.y = cvtpk(v2*w, v3*w);
                    *(uint2*)(k0base + (c*32 + ntk*16 + l15)*128 + ((unsigned)(mt*32 + g*8) ^ swz)) = pk;
                }
            }
        }
        f32x4 acc1[8];
        #pragma unroll
        for (int i=0;i<8;++i) acc1[i] = z4;
        #pragma unroll
        for (int c=0;c<3;++c){
            #pragma unroll
            for (int ks=0;ks<2;++ks){
                unsigned co = ((unsigned)(ks*64 + g*16)) ^ swz;
                bf16x8 a0f = *(const bf16x8*)(k0base + (c*32 +      l15)*128 + co);
                bf16x8 a1f = *(const bf16x8*)(k0base + (c*32 + 16 + l15)*128 + co);
                #pragma unroll
                for (int nt=0;nt<4;++nt){
                    bf16x8 bfr = *(const bf16x8*)(SM + (c*64 + nt*16 + l15)*128 + co);
                    acc1[0*4+nt] = __builtin_amdgcn_mfma_f32_16x16x32_bf16(a0f, bfr, acc1[0*4+nt], 0,0,0);
                    acc1[1*4+nt] = __builtin_amdgcn_mfma_f32_16x16x32_bf16(a1f, bfr, acc1[1*4+nt], 0,0,0);
                }
            }
        }
        #pragma unroll
        for (int nt=0;nt<4;++nt){
            float vmx = -3.4e38f, vmn = 3.4e38f, s = 0.f, ssq = 0.f;
            #pragma unroll
            for (int mtk=0;mtk<2;++mtk){
                f32x4 a = acc1[mtk*4+nt];
                #pragma unroll
                for (int q=0;q<4;++q){
                    float v = a[q];
                    vmx = fmaxf(vmx, v); vmn = fminf(vmn, v);
                    s += v; ssq += v*v;
                }
            }
            vmx = fmaxf(vmx, __shfl_xor(vmx, 16)); vmn = fminf(vmn, __shfl_xor(vmn, 16));
            s  += __shfl_xor(s, 16);               ssq += __shfl_xor(ssq, 16);
            vmx = fmaxf(vmx, __shfl_xor(vmx, 32)); vmn = fminf(vmn, __shfl_xor(vmn, 32));
            s  += __shfl_xor(s, 32);               ssq += __shfl_xor(ssq, 32);
            if (lane < 16){
                mx[(size_t)n*CH + nt*16 + l15] = vmx;
                mn[(size_t)n*CH + nt*16 + l15] = vmn;
                ps[nt] += s; pss[nt] += ssq;
            }
        }
    }
    __syncthreads();
    float* red = (float*)SM;
    if (lane < 16){
        #pragma unroll
        for (int nt=0;nt<4;++nt){
            red[warp*128 + nt*16 + l15]        = ps[nt];
            red[1024 + warp*128 + nt*16 + l15] = pss[nt];
        }
    }
    __syncthreads();
    if (tid < 64){
        float s = 0.f, ssq = 0.f;
        #pragma unroll
        for (int w8=0;w8<8;++w8){ s += red[w8*128 + tid]; ssq += red[1024 + w8*128 + tid]; }
        msgpart[(size_t)bid*128 + tid]      = s;
        msgpart[(size_t)bid*128 + 64 + tid] = ssq;
    }
}

// ---------- K7: msg aggregation with folded fd1 ----------
__global__ __launch_bounds__(512) void k7_agg(const float* __restrict__ mxb, const float* __restrict__ mnb,
    const float* __restrict__ msgpart, const float* __restrict__ gb1, const float* __restrict__ bb1,
    float* __restrict__ aggb, float* __restrict__ aggpart, int N)
{
    __shared__ float r1[512], r2[512];
    __shared__ float a1ms[64], c1ms[64];
    int tid = threadIdx.x, bid = blockIdx.x;
    {
        int t = tid & 63, seg = tid >> 6;
        float s = 0.f, ss = 0.f;
        for (int r = seg; r < CONV_GRID; r += 8){ s += msgpart[r*128 + t]; ss += msgpart[r*128 + 64 + t]; }
        r1[tid] = s; r2[tid] = ss;
    }
    __syncthreads();
    if (tid < 64){
        float S = 0.f, SS = 0.f;
        #pragma unroll
        for (int k=0;k<8;++k){ S += r1[tid + 64*k]; SS += r2[tid + 64*k]; }
        float invc = 1.0f/((float)N*KNB);
        float m = S*invc, var = SS*invc - m*m;
        float ai = gb1[tid]*rsqrtf(var + BN_EPS);
        a1ms[tid] = ai; c1ms[tid] = bb1[tid] - m*ai;
    }
    __syncthreads();
    int h = tid & 63;
    float ah = a1ms[h], chh = c1ms[h];
    bool useMax = (ah >= 0.f);
    float ps = 0.f, pss = 0.f;
    for (int i = bid*512 + tid; i < N*CH; i += gridDim.x*512){
        float sel = useMax ? mxb[i] : mnb[i];
        float v = leakyf(ah*sel + chh);
        aggb[i] = v; ps += v; pss += v*v;
    }
    __syncthreads();
    r1[tid] = ps; r2[tid] = pss;
    __syncthreads();
    if (tid < 64){
        float S = 0.f, SS = 0.f;
        #pragma unroll
        for (int k=0;k<8;++k){ S += r1[tid + 64*k]; SS += r2[tid + 64*k]; }
        aggpart[(size_t)bid*128 + tid]      = S;
        aggpart[(size_t)bid*128 + 64 + tid] = SS;
    }
}

// ---------- K8: fold fd2 + transform agg -> a2b2 + gram64 partials -> slabC ----------
__global__ __launch_bounds__(512) void k8_gram64t(const float* __restrict__ aggb, const float* __restrict__ aggpart,
    const float* __restrict__ gbc, const float* __restrict__ bbc,
    ushort* __restrict__ a2b2, float* __restrict__ slabC, int N)
{
    __shared__ ushort Xt[64][72];
    __shared__ float red[32][64];
    __shared__ float abncs[64], cbncs[64];
    int tid = threadIdx.x, bid = blockIdx.x;
    int wave = tid >> 6, lane = tid & 63, l15 = lane & 15, g = lane >> 4;
    const f32x4 z4 = {0.f,0.f,0.f,0.f};
    {
        float* r1 = &red[0][0]; float* r2 = r1 + 512;
        int t = tid & 63, seg = tid >> 6;
        float s = 0.f, ss = 0.f;
        for (int r = seg; r < 256; r += 8){ s += aggpart[r*128 + t]; ss += aggpart[r*128 + 64 + t]; }
        r1[tid] = s; r2[tid] = ss;
        __syncthreads();
        if (tid < 64){
            float S = 0.f, SS = 0.f;
            #pragma unroll
            for (int k=0;k<8;++k){ S += r1[tid + 64*k]; SS += r2[tid + 64*k]; }
            float invc = 1.0f/(float)N;
            float m = S*invc, var = SS*invc - m*m;
            float ai = gbc[tid]*rsqrtf(var + BN_EPS);
            abncs[tid] = ai; cbncs[tid] = bbc[tid] - m*ai;
        }
        __syncthreads();
    }
    int wr = wave >> 1, wc = wave & 1;
    f32x4 acc[2] = {z4, z4};
    float pcs[4] = {0,0,0,0};
    int nch = (N + 63) >> 6;
    for (int ch = bid; ch < nch; ch += 256){
        int base = ch << 6;
        __syncthreads();
        #pragma unroll
        for (int ii=0;ii<2;++ii){
            int i = tid + ii*512;
            int r = i >> 4, cq = i & 15;
            int n = base + r;
            float4 v = make_float4(0.f,0.f,0.f,0.f);
            if (n < N){
                v = ((const float4*)aggb)[(size_t)n*16 + cq];
                v.x = leakyf(abncs[cq*4+0]*v.x + cbncs[cq*4+0]);
                v.y = leakyf(abncs[cq*4+1]*v.y + cbncs[cq*4+1]);
                v.z = leakyf(abncs[cq*4+2]*v.z + cbncs[cq*4+2]);
                v.w = leakyf(abncs[cq*4+3]*v.w + cbncs[cq*4+3]);
            }
            uint2 pk; pk.x = cvtpk(v.x, v.y); pk.y = cvtpk(v.z, v.w);
            if (n < N) ((uint2*)a2b2)[(size_t)n*16 + cq] = pk;
            Xt[cq*4+0][r] = (ushort)(pk.x & 0xffff);
            Xt[cq*4+1][r] = (ushort)(pk.x >> 16);
            Xt[cq*4+2][r] = (ushort)(pk.y & 0xffff);
            Xt[cq*4+3][r] = (ushort)(pk.y >> 16);
            pcs[0] += v.x; pcs[1] += v.y; pcs[2] += v.z; pcs[3] += v.w;
        }
        __syncthreads();
        #pragma unroll
        for (int ks=0;ks<2;++ks){
            bf16x8 af = *(const bf16x8*)&Xt[wr*16 + l15][ks*32 + g*8];
            #pragma unroll
            for (int u=0;u<2;++u){
                bf16x8 bv = *(const bf16x8*)&Xt[wc*32 + u*16 + l15][ks*32 + g*8];
                acc[u] = __builtin_amdgcn_mfma_f32_16x16x32_bf16(af, bv, acc[u], 0,0,0);
            }
        }
    }
    float* Gp = slabC + (size_t)bid*4160;
    #pragma unroll
    for (int u=0;u<2;++u)
        #pragma unroll
        for (int q=0;q<4;++q)
            Gp[(wr*16 + g*4 + q)*CH + wc*32 + u*16 + l15] = acc[u][q];
    __syncthreads();
    { int r = tid >> 4, cq = tid & 15;
      #pragma unroll
      for (int j=0;j<4;++j) red[r][cq*4+j] = pcs[j]; }
    __syncthreads();
    if (tid < CH){
        float s = 0.f;
        #pragma unroll
        for (int k=0;k<32;++k) s += red[k][tid];
        Gp[4096 + tid] = s;
    }
}

// ---------- K10: finalize unary2 BN + wcat[:,128:192] + ccomb from reduced G2 ----------
__global__ __launch_bounds__(512) void k10_fin2(const float* __restrict__ G2, const float* __restrict__ s2,
    const float* __restrict__ Wu2, const float* __restrict__ g2, const float* __restrict__ b2,
    const float* __restrict__ cscv, float invN, ushort* __restrict__ wcat, float* __restrict__ ccomb)
{
    int gw = blockIdx.x*8 + (threadIdx.x >> 6), lane = threadIdx.x & 63;
    if (gw < 256){
        float ai, ci;
        bn_affine_wave(G2, s2, Wu2, g2, b2, invN, CH, COUT, gw, lane, ai, ci);
        wcat[gw*192 + 128 + lane] = f2bf(ai*Wu2[lane*COUT + gw]);
        if (lane == 0) ccomb[gw] = cscv[gw] + ci;
    }
}

// ---------- K11: final GEMM [feat|a2] @ wcat^T -> out ----------
__global__ __launch_bounds__(512) void final_mfma_kernel(
    const ushort* __restrict__ featbf, const ushort* __restrict__ a2b2,
    const ushort* __restrict__ wcat, const float* __restrict__ ccomb,
    float* __restrict__ out, int N)
{
    int tid = threadIdx.x, wave = tid >> 6, lane = tid & 63;
    int l15 = lane & 15, g = lane >> 4;
    int row0 = blockIdx.x*128 + wave*16;
    const f32x4 z4 = {0.f,0.f,0.f,0.f};
    f32x4 acc[16];
    #pragma unroll
    for (int i=0;i<16;++i) acc[i] = z4;
    int r = row0 + l15;
    bool ok = r < N;
    #pragma unroll
    for (int s=0;s<6;++s){
        bf16x8 af = {0,0,0,0,0,0,0,0};
        if (ok){
            const ushort* srcp = (s < 4) ? (featbf + (size_t)r*CIN + s*32 + g*8)
                                         : (a2b2  + (size_t)r*CH + (s-4)*32 + g*8);
            af = *(const bf16x8*)srcp;
        }
        #pragma unroll
        for (int nt=0;nt<16;++nt){
            bf16x8 bfr = *(const bf16x8*)(wcat + (size_t)(nt*16+l15)*192 + s*32 + g*8);
            acc[nt] = __builtin_amdgcn_mfma_f32_16x16x32_bf16(af, bfr, acc[nt], 0,0,0);
        }
    }
    #pragma unroll
    for (int nt=0;nt<16;++nt){
        float cc = ccomb[nt*16 + l15];
        #pragma unroll
        for (int q=0;q<4;++q){
            int rr = row0 + g*4 + q;
            if (rr < N) out[(size_t)rr*COUT + nt*16 + l15] = leakyf(acc[nt][q] + cc);
        }
    }
}

extern "C" void kernel_launch(void* const* d_in, const int* in_sizes, int n_in,
                              void* d_out, int out_size, void* d_ws, size_t ws_size,
                              hipStream_t stream)
{
    const float* feat = (const float*)d_in[0];
    const float* qp   = (const float*)d_in[1];
    const float* sp   = (const float*)d_in[2];
    const int*   inds = (const int*)d_in[3];
    const float* Wu1  = (const float*)d_in[4];
    const float* g1   = (const float*)d_in[5];
    const float* b1   = (const float*)d_in[6];
    const float* W0   = (const float*)d_in[7];
    const float* gb0  = (const float*)d_in[8];
    const float* bb0  = (const float*)d_in[9];
    const float* W1   = (const float*)d_in[10];
    const float* gb1  = (const float*)d_in[11];
    const float* bb1  = (const float*)d_in[12];
    const float* gbc  = (const float*)d_in[13];
    const float* bbc  = (const float*)d_in[14];
    const float* Wu2  = (const float*)d_in[15];
    const float* g2   = (const float*)d_in[16];
    const float* b2   = (const float*)d_in[17];
    const float* Wsc  = (const float*)d_in[18];
    const float* gsc  = (const float*)d_in[19];
    const float* bsc  = (const float*)d_in[20];

    const int N = in_sizes[0] / CIN;           // 20000

    float* ws   = (float*)d_ws;
    float* XtX  = ws;                              // 16384 + 128
    float* fsum = ws + 16384;
    float* G0   = ws + 16512;                      // 4096 + 64
    float* s0   = G0 + 4096;
    float* G2   = ws + 16512 + 4160;               // 4096 + 64
    float* s2   = G2 + 4096;
    float* cnt  = ws + 16512 + 8320;               // N
    float* prm  = cnt + N;                         // 1536
    float* c1v  = prm + 64;
    float* c0p  = prm + 192;
    float* cscv = prm + 768;
    float* msgpart = prm + 1536;                   // CONV_GRID*128
    float* aggpart = msgpart + CONV_GRID*128;      // 256*128
    float* mxb  = aggpart + 256*128;               // N*64
    float* mnb  = mxb + (size_t)N*CH;              // N*64
    float* aggb = mnb + (size_t)N*CH;              // N*64
    ushort* xbf    = (ushort*)(aggb + (size_t)N*CH);
    ushort* featbf = xbf + (size_t)(N+1)*CH;
    ushort* a2b2   = featbf + (size_t)N*CIN;
    ushort* w1s    = a2b2 + (size_t)N*CH;          // 192*64
    ushort* wcat   = w1s + 192*CH;                 // 256*192
    ushort* w1t    = wcat + COUT*192;              // 64*128
    ushort* w0t    = w1t + CH*CIN;                 // 64*64
    float*  ccomb  = (float*)(w0t + CH*CH);        // 256

    // slab aliasing (stream-order safe):
    float* slabA = mxb;     // 128*16512 <= 2*N*CH   (dead until conv writes mx/mn)
    float* slabB = aggb;    // 157*4160  <= N*CH     (dead until k7 writes aggb)
    float* slabC = mxb;     // 256*4160  <= N*CH     (mxb consumed by k7 before k8)

    const int nTiles = (N + 127)/128;              // 157

    hipMemsetAsync(cnt, 0, (size_t)N*sizeof(float), stream);
    k1_kernel<<<256, 512, 0, stream>>>(feat, inds, W1, N, slabA, featbf, w1s, xbf, cnt);
    reduce_slab<<<(16512 + 255)/256, 256, 0, stream>>>(slabA, 128, 16512, XtX);
    k3_finA<<<40, 512, 0, stream>>>(XtX, fsum, Wu1, g1, b1, Wsc, gsc, bsc, 1.0f/N, c1v, w1t, wcat, cscv);
    k4_unary1_gram<<<nTiles, 512, 0, stream>>>(featbf, w1t, c1v, cnt, xbf, slabB, N);
    reduce_slab<<<(4160 + 255)/256, 256, 0, stream>>>(slabB, nTiles, 4160, G0);
    k5_fin0<<<8, 512, 0, stream>>>(G0, s0, W0, gb0, bb0, 1.0f/((float)N*KNB), c0p, w0t);
    conv_msg_mfma<<<CONV_GRID, 512, 0, stream>>>(xbf, qp, sp, inds, w0t, w1s, c0p, mxb, mnb, msgpart, N);
    k7_agg<<<256, 512, 0, stream>>>(mxb, mnb, msgpart, gb1, bb1, aggb, aggpart, N);
    k8_gram64t<<<256, 512, 0, stream>>>(aggb, aggpart, gbc, bbc, a2b2, slabC, N);
    reduce_slab<<<(4160 + 255)/256, 256, 0, stream>>>(slabC, 256, 4160, G2);
    k10_fin2<<<32, 512, 0, stream>>>(G2, s2, Wu2, g2, b2, cscv, 1.0f/N, wcat, ccomb);
    final_mfma_kernel<<<nTiles, 512, 0, stream>>>(featbf, a2b2, wcat, ccomb, (float*)d_out, N);
}

// Round 13
// 231.331 us; speedup vs baseline: 1.3225x; 1.0061x over previous
//
#include <hip/hip_runtime.h>

#define KNB 32
#define CIN 128
#define CH 64
#define COUT 256
#define BN_EPS 1e-5f
#define CONV_GRID 256

typedef __attribute__((ext_vector_type(8))) short bf16x8;
typedef __attribute__((ext_vector_type(4))) float f32x4;

static __device__ __forceinline__ float leakyf(float v){ return fmaxf(v, 0.1f*v); }

static __device__ __forceinline__ unsigned short f2bf(float f){
    unsigned u = __float_as_uint(f);
    u += 0x7FFFu + ((u >> 16) & 1u);
    return (unsigned short)(u >> 16);
}
static __device__ __forceinline__ float bf2f(ushort u){ return __uint_as_float(((unsigned)u) << 16); }

static __device__ __forceinline__ unsigned cvtpk(float lo, float hi){
    unsigned r;
    asm("v_cvt_pk_bf16_f32 %0, %1, %2" : "=v"(r) : "v"(lo), "v"(hi));
    return r;
}

// per-wave BN affine from SYMMETRIC Gram/colsum; coalesced: lane indexes the
// contiguous dim of G (pq = w^T G^T w = w^T G w). W[i*M+o] inner reads are
// wave-uniform broadcasts. G must be L1/L2-resident (16KB).
static __device__ __forceinline__ void bn_affine_wave(const float* __restrict__ G, const float* __restrict__ s,
    const float* __restrict__ W, const float* __restrict__ gg, const float* __restrict__ bb,
    float invcnt, int D, int M, int o, int lane, float& ai, float& ci)
{
    float pm = 0.f, pq = 0.f;
    for (int j = lane; j < D; j += 64){
        float wj = W[j*M + o];
        pm += s[j]*wj;
        float t = 0.f;
        for (int i = 0; i < D; ++i) t += G[i*D + j]*W[i*M + o];
        pq += wj*t;
    }
    #pragma unroll
    for (int off = 32; off; off >>= 1){
        pm += __shfl_down(pm, off);
        pq += __shfl_down(pq, off);
    }
    float m  = pm*invcnt;
    float var = pq*invcnt - m*m;
    float a_ = gg[o]*rsqrtf(var + BN_EPS);
    float c_ = bb[o] - m*a_;
    ai = __shfl(a_, 0);
    ci = __shfl(c_, 0);
}

// ---------- K1 split-grid: [0,128) gram128 partials + featbf write ; [128,256) hist+w1s+shadow ----------
__global__ __launch_bounds__(512) void k1_kernel(const float* __restrict__ feat, const int* __restrict__ inds,
    const float* __restrict__ W1, int N,
    float* __restrict__ slabA, ushort* __restrict__ featbf, ushort* __restrict__ w1s,
    ushort* __restrict__ xbf, float* __restrict__ cnt)
{
    __shared__ ushort Xt[128][40];
    __shared__ float red[16][128];
    int tid = threadIdx.x, bid = blockIdx.x;
    if (bid < 128){
        int wave = tid >> 6, lane = tid & 63, l15 = lane & 15, g = lane >> 4;
        int wr = wave >> 1, wc = wave & 1;
        const f32x4 z4 = {0.f,0.f,0.f,0.f};
        f32x4 acc[2][4];
        #pragma unroll
        for (int i=0;i<2;++i)
            #pragma unroll
            for (int j=0;j<4;++j) acc[i][j] = z4;
        float pcs[4] = {0,0,0,0};
        int nch = (N + 31) >> 5;
        for (int ch = bid; ch < nch; ch += 128){
            int base = ch << 5;
            __syncthreads();
            #pragma unroll
            for (int ii=0; ii<2; ++ii){
                int i = tid + ii*512;
                int r = i >> 5, c4 = i & 31;
                int n = base + r;
                float4 v = make_float4(0.f,0.f,0.f,0.f);
                if (n < N) v = ((const float4*)feat)[(size_t)n*32 + c4];
                ushort b0=f2bf(v.x), b1=f2bf(v.y), b2=f2bf(v.z), b3=f2bf(v.w);
                Xt[c4*4+0][r]=b0; Xt[c4*4+1][r]=b1; Xt[c4*4+2][r]=b2; Xt[c4*4+3][r]=b3;
                pcs[0]+=bf2f(b0); pcs[1]+=bf2f(b1); pcs[2]+=bf2f(b2); pcs[3]+=bf2f(b3);
                if (n < N){
                    uint2 pk;
                    pk.x = (unsigned)b0 | ((unsigned)b1 << 16);
                    pk.y = (unsigned)b2 | ((unsigned)b3 << 16);
                    ((uint2*)featbf)[(size_t)n*32 + c4] = pk;
                }
            }
            __syncthreads();
            bf16x8 af[2], bv[4];
            #pragma unroll
            for (int t=0;t<2;++t) af[t] = *(const bf16x8*)&Xt[wr*32 + t*16 + l15][g*8];
            #pragma unroll
            for (int u=0;u<4;++u) bv[u] = *(const bf16x8*)&Xt[wc*64 + u*16 + l15][g*8];
            #pragma unroll
            for (int t=0;t<2;++t)
                #pragma unroll
                for (int u=0;u<4;++u)
                    acc[t][u] = __builtin_amdgcn_mfma_f32_16x16x32_bf16(af[t], bv[u], acc[t][u], 0,0,0);
        }
        float* Gp = slabA + (size_t)bid*16512;
        #pragma unroll
        for (int t=0;t<2;++t)
            #pragma unroll
            for (int u=0;u<4;++u)
                #pragma unroll
                for (int q=0;q<4;++q)
                    Gp[(wr*32 + t*16 + g*4 + q)*CIN + wc*64 + u*16 + l15] = acc[t][u][q];
        __syncthreads();
        { int r16 = tid >> 5, c4 = tid & 31;
          #pragma unroll
          for (int j=0;j<4;++j) red[r16][c4*4+j] = pcs[j]; }
        __syncthreads();
        if (tid < CIN){
            float s = 0.f;
            #pragma unroll
            for (int k=0;k<16;++k) s += red[k][tid];
            Gp[16384 + tid] = s;
        }
    } else {
        int t2 = (bid-128)*512 + tid;
        const int TG = 128*512;
        for (int i = t2; i < N*KNB; i += TG){
            int ix = inds[i];
            if ((unsigned)ix < (unsigned)N) atomicAdd(&cnt[ix], 1.0f);
        }
        if (t2 < 192*CH){
            int r = t2 >> 6, dd = t2 & 63;
            int c = r >> 6, h = r & 63;
            w1s[t2] = f2bf(W1[dd*192 + 3*h + c]);
        }
        if (t2 < CH) xbf[(size_t)N*CH + t2] = 0;
    }
}

// ---------- reduce per-block partial slabs (4 independent accumulator chains) ----------
__global__ __launch_bounds__(256) void reduce_slab(const float* __restrict__ slab, int nparts, int len,
                                                   float* __restrict__ dst)
{
    int j = blockIdx.x*256 + threadIdx.x;
    if (j < len){
        float s0 = 0.f, s1 = 0.f, s2 = 0.f, s3 = 0.f;
        int b = 0;
        for (; b + 4 <= nparts; b += 4){
            s0 += slab[(size_t)(b+0)*len + j];
            s1 += slab[(size_t)(b+1)*len + j];
            s2 += slab[(size_t)(b+2)*len + j];
            s3 += slab[(size_t)(b+3)*len + j];
        }
        for (; b < nparts; ++b) s0 += slab[(size_t)b*len + j];
        dst[j] = (s0 + s1) + (s2 + s3);
    }
}

// ---------- K3: finalize a1/c1 + w1t  and  asc/csc + wcat[:,0:128] ----------
__global__ __launch_bounds__(512) void k3_finA(const float* __restrict__ XtX, const float* __restrict__ fsum,
    const float* __restrict__ Wu1, const float* __restrict__ g1, const float* __restrict__ b1,
    const float* __restrict__ Wsc, const float* __restrict__ gsc, const float* __restrict__ bsc,
    float invN, float* __restrict__ c1v, ushort* __restrict__ w1t,
    ushort* __restrict__ wcat, float* __restrict__ cscv)
{
    int gw = blockIdx.x*8 + (threadIdx.x >> 6), lane = threadIdx.x & 63;
    if (gw < 64){
        int o = gw; float ai, ci;
        bn_affine_wave(XtX, fsum, Wu1, g1, b1, invN, CIN, CH, o, lane, ai, ci);
        if (lane == 0) c1v[o] = ci;
        for (int k = lane; k < CIN; k += 64) w1t[o*CIN + k] = f2bf(ai*Wu1[k*CH + o]);
    } else if (gw < 320){
        int o = gw - 64; float ai, ci;
        bn_affine_wave(XtX, fsum, Wsc, gsc, bsc, invN, CIN, COUT, o, lane, ai, ci);
        if (lane == 0) cscv[o] = ci;
        for (int k = lane; k < CIN; k += 64) wcat[o*192 + k] = f2bf(ai*Wsc[k*COUT + o]);
    }
}

// ---------- K4: unary1 MFMA -> xbf  +  fused weighted gram64 partials -> slabB ----------
__global__ __launch_bounds__(512) void k4_unary1_gram(const ushort* __restrict__ featbf,
    const ushort* __restrict__ w1t, const float* __restrict__ c1v, const float* __restrict__ cnt,
    ushort* __restrict__ xbf, float* __restrict__ slabB, int N)
{
    __shared__ ushort Xp[64][136];    // plain bf16, [channel][localrow]
    __shared__ ushort Xw[64][136];    // cnt-weighted bf16
    __shared__ float red[8][64];
    int tid = threadIdx.x, bid = blockIdx.x;
    int wave = tid >> 6, lane = tid & 63, l15 = lane & 15, g = lane >> 4;
    const f32x4 z4 = {0.f,0.f,0.f,0.f};
    int row0 = bid*128 + wave*16;
    f32x4 acc[4] = {z4, z4, z4, z4};
    int r = row0 + l15;
    bool ok = r < N;
    #pragma unroll
    for (int s=0;s<4;++s){
        bf16x8 af = {0,0,0,0,0,0,0,0};
        if (ok) af = *(const bf16x8*)(featbf + (size_t)r*CIN + s*32 + g*8);
        #pragma unroll
        for (int nt=0;nt<4;++nt){
            bf16x8 bfr = *(const bf16x8*)(w1t + (size_t)(nt*16+l15)*CIN + s*32 + g*8);
            acc[nt] = __builtin_amdgcn_mfma_f32_16x16x32_bf16(af, bfr, acc[nt], 0,0,0);
        }
    }
    float wq[4];
    #pragma unroll
    for (int q=0;q<4;++q){
        int rr = row0 + g*4 + q;
        wq[q] = (rr < N) ? cnt[rr] : 0.f;
    }
    float ps[4] = {0,0,0,0};
    #pragma unroll
    for (int nt=0;nt<4;++nt){
        int col = nt*16 + l15;
        float cc = c1v[col];
        #pragma unroll
        for (int q=0;q<4;++q){
            int rr = row0 + g*4 + q;
            int lr = wave*16 + g*4 + q;
            float v = (rr < N) ? leakyf(acc[nt][q] + cc) : 0.f;
            ushort b = f2bf(v);
            if (rr < N) xbf[(size_t)rr*CH + col] = b;
            Xp[col][lr] = b;
            float wv = wq[q]*v;
            Xw[col][lr] = f2bf(wv);
            ps[nt] += wv;
        }
    }
    #pragma unroll
    for (int nt=0;nt<4;++nt){
        ps[nt] += __shfl_xor(ps[nt], 16);
        ps[nt] += __shfl_xor(ps[nt], 32);
        if (lane < 16) red[wave][nt*16 + l15] = ps[nt];
    }
    __syncthreads();
    // gram over this block's 128 rows: wave -> (mr = wave>>1, cols (wave&1)*2 + {0,1})
    int mr = wave >> 1, ncb = (wave & 1)*2;
    f32x4 ac2[2] = {z4, z4};
    #pragma unroll
    for (int ks=0;ks<4;++ks){
        bf16x8 af = *(const bf16x8*)&Xw[mr*16 + l15][ks*32 + g*8];
        #pragma unroll
        for (int u=0;u<2;++u){
            bf16x8 bv = *(const bf16x8*)&Xp[(ncb+u)*16 + l15][ks*32 + g*8];
            ac2[u] = __builtin_amdgcn_mfma_f32_16x16x32_bf16(af, bv, ac2[u], 0,0,0);
        }
    }
    float* Gp = slabB + (size_t)bid*4160;
    #pragma unroll
    for (int u=0;u<2;++u)
        #pragma unroll
        for (int q=0;q<4;++q)
            Gp[(mr*16 + g*4 + q)*CH + (ncb+u)*16 + l15] = ac2[u][q];
    if (tid < CH){
        float s = 0.f;
        #pragma unroll
        for (int w8=0;w8<8;++w8) s += red[w8][tid];
        Gp[4096 + tid] = s;
    }
}

// ---------- K5: finalize a0/c0 + w0t from reduced G0 (8 blocks) ----------
__global__ __launch_bounds__(512) void k5_fin0(const float* __restrict__ G0, const float* __restrict__ s0,
    const float* __restrict__ W0, const float* __restrict__ gb0, const float* __restrict__ bb0,
    float invNK, float* __restrict__ c0p, ushort* __restrict__ w0t)
{
    int gw = blockIdx.x*8 + (threadIdx.x >> 6), lane = threadIdx.x & 63;
    if (gw < 64){
        float ai, ci;
        bn_affine_wave(G0, s0, W0, gb0, bb0, invNK, CH, CH, gw, lane, ai, ci);
        if (lane == 0) c0p[gw] = ci;
        w0t[gw*CH + lane] = f2bf(ai*W0[lane*CH + gw]);
    }
}

// ---------- K6: conv0/conv1 message + stats (round-7 body + software-pipelined gathers) ----------
__global__ __launch_bounds__(512) void conv_msg_mfma(
    const ushort* __restrict__ xbf, const float* __restrict__ qp, const float* __restrict__ sp,
    const int* __restrict__ inds, const ushort* __restrict__ w0t, const ushort* __restrict__ w1s,
    const float* __restrict__ c0p,
    float* __restrict__ mx, float* __restrict__ mn, float* __restrict__ msgpart, int N)
{
    __shared__ unsigned char SM[24576 + 8*12288];
    int tid = threadIdx.x, bid = blockIdx.x;
    int warp = tid >> 6, lane = tid & 63;
    int l15 = lane & 15, g = lane >> 4;
    // stage w1s swizzled
    for (int ch = tid; ch < 1536; ch += 512){
        int r = ch >> 3, c16 = ch & 7;
        uint4 v = ((const uint4*)w1s)[ch];
        *(uint4*)(SM + r*128 + ((c16*16) ^ ((r&7)<<4))) = v;
    }
    bf16x8 wf[8];
    #pragma unroll
    for (int mt=0;mt<4;++mt)
        #pragma unroll
        for (int s=0;s<2;++s)
            wf[mt*2+s] = *(const bf16x8*)(w0t + (mt*16+l15)*CH + s*32 + g*8);
    float c0r[16];
    #pragma unroll
    for (int mt=0;mt<4;++mt)
        #pragma unroll
        for (int q=0;q<4;++q)
            c0r[mt*4+q] = c0p[mt*16 + g*4 + q];
    unsigned char* k0base = SM + 24576 + warp*12288;
    unsigned swz = (unsigned)((l15 & 7) << 4);
    float ps[4] = {0,0,0,0}, pss[4] = {0,0,0,0};
    const f32x4 z4 = {0.f,0.f,0.f,0.f};
    const int stride = CONV_GRID*8;
    __syncthreads();

    // ---- software pipeline: prefetch stage for first point ----
    int n0 = bid*8 + warp;
    int ix0 = N, ix1 = N;
    bf16x8 xf0a = {0,0,0,0,0,0,0,0}, xf0b = xf0a, xf1a = xf0a, xf1b = xf0a;
    float nbv[2][3] = {{0,0,0},{0,0,0}};
    if (n0 < N){
        ix0 = inds[n0*KNB + l15];
        ix1 = inds[n0*KNB + 16 + l15];
        if ((unsigned)ix0 > (unsigned)N) ix0 = N;
        if ((unsigned)ix1 > (unsigned)N) ix1 = N;
        xf0a = *(const bf16x8*)(xbf + (size_t)ix0*CH +      g*8);
        xf0b = *(const bf16x8*)(xbf + (size_t)ix0*CH + 32 + g*8);
        xf1a = *(const bf16x8*)(xbf + (size_t)ix1*CH +      g*8);
        xf1b = *(const bf16x8*)(xbf + (size_t)ix1*CH + 32 + g*8);
        float qx = qp[n0*3+0], qy = qp[n0*3+1], qz = qp[n0*3+2];
        if (ix0 < N){ nbv[0][0]=sp[ix0*3]-qx; nbv[0][1]=sp[ix0*3+1]-qy; nbv[0][2]=sp[ix0*3+2]-qz; }
        else        { nbv[0][0]=-qx; nbv[0][1]=-qy; nbv[0][2]=-qz; }
        if (ix1 < N){ nbv[1][0]=sp[ix1*3]-qx; nbv[1][1]=sp[ix1*3+1]-qy; nbv[1][2]=sp[ix1*3+2]-qz; }
        else        { nbv[1][0]=-qx; nbv[1][1]=-qy; nbv[1][2]=-qz; }
    }

    for (int n = n0; n < N; n += stride){
        int nn = n + stride;
        // prefetch next indices (first link of next chain) immediately
        int jx0 = N, jx1 = N;
        if (nn < N){
            jx0 = inds[nn*KNB + l15];
            jx1 = inds[nn*KNB + 16 + l15];
            if ((unsigned)jx0 > (unsigned)N) jx0 = N;
            if ((unsigned)jx1 > (unsigned)N) jx1 = N;
        }
        // conv0: consumes current xf
        f32x4 acc0[8];
        #pragma unroll
        for (int i=0;i<8;++i) acc0[i] = z4;
        #pragma unroll
        for (int mt=0;mt<4;++mt){
            acc0[mt*2+0] = __builtin_amdgcn_mfma_f32_16x16x32_bf16(wf[mt*2+0], xf0a, acc0[mt*2+0], 0,0,0);
            acc0[mt*2+0] = __builtin_amdgcn_mfma_f32_16x16x32_bf16(wf[mt*2+1], xf0b, acc0[mt*2+0], 0,0,0);
            acc0[mt*2+1] = __builtin_amdgcn_mfma_f32_16x16x32_bf16(wf[mt*2+0], xf1a, acc0[mt*2+1], 0,0,0);
            acc0[mt*2+1] = __builtin_amdgcn_mfma_f32_16x16x32_bf16(wf[mt*2+1], xf1b, acc0[mt*2+1], 0,0,0);
        }
        // issue next xf gathers while conv0 MFMAs drain
        bf16x8 yf0a = {0,0,0,0,0,0,0,0}, yf0b = yf0a, yf1a = yf0a, yf1b = yf0a;
        if (nn < N){
            yf0a = *(const bf16x8*)(xbf + (size_t)jx0*CH +      g*8);
            yf0b = *(const bf16x8*)(xbf + (size_t)jx0*CH + 32 + g*8);
            yf1a = *(const bf16x8*)(xbf + (size_t)jx1*CH +      g*8);
            yf1b = *(const bf16x8*)(xbf + (size_t)jx1*CH + 32 + g*8);
        }
        // pack k0c (bn0 + leaky + nbx scale), uses current nbv
        #pragma unroll
        for (int mt=0;mt<4;++mt){
            #pragma unroll
            for (int ntk=0;ntk<2;++ntk){
                f32x4 a = acc0[mt*2+ntk];
                float v0 = leakyf(a[0] + c0r[mt*4+0]);
                float v1 = leakyf(a[1] + c0r[mt*4+1]);
                float v2 = leakyf(a[2] + c0r[mt*4+2]);
                float v3 = leakyf(a[3] + c0r[mt*4+3]);
                #pragma unroll
                for (int c=0;c<3;++c){
                    float w = nbv[ntk][c];
                    uint2 pk;
                    pk.x = cvtpk(v0*w, v1*w);
                    pk.y = cvtpk(v2*w, v3*w);
                    *(uint2*)(k0base + (c*32 + ntk*16 + l15)*128 + ((unsigned)(mt*32 + g*8) ^ swz)) = pk;
                }
            }
        }
        // conv1
        f32x4 acc1[8];
        #pragma unroll
        for (int i=0;i<8;++i) acc1[i] = z4;
        #pragma unroll
        for (int c=0;c<3;++c){
            #pragma unroll
            for (int ks=0;ks<2;++ks){
                unsigned co = ((unsigned)(ks*64 + g*16)) ^ swz;
                bf16x8 a0f = *(const bf16x8*)(k0base + (c*32 +      l15)*128 + co);
                bf16x8 a1f = *(const bf16x8*)(k0base + (c*32 + 16 + l15)*128 + co);
                #pragma unroll
                for (int nt=0;nt<4;++nt){
                    bf16x8 bfr = *(const bf16x8*)(SM + (c*64 + nt*16 + l15)*128 + co);
                    acc1[0*4+nt] = __builtin_amdgcn_mfma_f32_16x16x32_bf16(a0f, bfr, acc1[0*4+nt], 0,0,0);
                    acc1[1*4+nt] = __builtin_amdgcn_mfma_f32_16x16x32_bf16(a1f, bfr, acc1[1*4+nt], 0,0,0);
                }
            }
        }
        // prefetch next nbv (qp/sp loads) under conv1 drain
        float mbv[2][3] = {{0,0,0},{0,0,0}};
        if (nn < N){
            float qx = qp[nn*3+0], qy = qp[nn*3+1], qz = qp[nn*3+2];
            if (jx0 < N){ mbv[0][0]=sp[jx0*3]-qx; mbv[0][1]=sp[jx0*3+1]-qy; mbv[0][2]=sp[jx0*3+2]-qz; }
            else        { mbv[0][0]=-qx; mbv[0][1]=-qy; mbv[0][2]=-qz; }
            if (jx1 < N){ mbv[1][0]=sp[jx1*3]-qx; mbv[1][1]=sp[jx1*3+1]-qy; mbv[1][2]=sp[jx1*3+2]-qz; }
            else        { mbv[1][0]=-qx; mbv[1][1]=-qy; mbv[1][2]=-qz; }
        }
        // reduce over k + stats
        #pragma unroll
        for (int nt=0;nt<4;++nt){
            float vmx = -3.4e38f, vmn = 3.4e38f, s = 0.f, ssq = 0.f;
            #pragma unroll
            for (int mtk=0;mtk<2;++mtk){
                f32x4 a = acc1[mtk*4+nt];
                #pragma unroll
                for (int q=0;q<4;++q){
                    float v = a[q];
                    vmx = fmaxf(vmx, v); vmn = fminf(vmn, v);
                    s += v; ssq += v*v;
                }
            }
            vmx = fmaxf(vmx, __shfl_xor(vmx, 16)); vmn = fminf(vmn, __shfl_xor(vmn, 16));
            s  += __shfl_xor(s, 16);               ssq += __shfl_xor(ssq, 16);
            vmx = fmaxf(vmx, __shfl_xor(vmx, 32)); vmn = fminf(vmn, __shfl_xor(vmn, 32));
            s  += __shfl_xor(s, 32);               ssq += __shfl_xor(ssq, 32);
            if (lane < 16){
                mx[(size_t)n*CH + nt*16 + l15] = vmx;
                mn[(size_t)n*CH + nt*16 + l15] = vmn;
                ps[nt] += s; pss[nt] += ssq;
            }
        }
        // rotate pipeline registers
        ix0 = jx0; ix1 = jx1;
        xf0a = yf0a; xf0b = yf0b; xf1a = yf1a; xf1b = yf1b;
        nbv[0][0]=mbv[0][0]; nbv[0][1]=mbv[0][1]; nbv[0][2]=mbv[0][2];
        nbv[1][0]=mbv[1][0]; nbv[1][1]=mbv[1][1]; nbv[1][2]=mbv[1][2];
    }
    __syncthreads();
    float* red = (float*)SM;
    if (lane < 16){
        #pragma unroll
        for (int nt=0;nt<4;++nt){
            red[warp*128 + nt*16 + l15]        = ps[nt];
            red[1024 + warp*128 + nt*16 + l15] = pss[nt];
        }
    }
    __syncthreads();
    if (tid < 64){
        float s = 0.f, ssq = 0.f;
        #pragma unroll
        for (int w8=0;w8<8;++w8){ s += red[w8*128 + tid]; ssq += red[1024 + w8*128 + tid]; }
        msgpart[(size_t)bid*128 + tid]      = s;
        msgpart[(size_t)bid*128 + 64 + tid] = ssq;
    }
}

// ---------- K7: msg aggregation with folded fd1 ----------
__global__ __launch_bounds__(512) void k7_agg(const float* __restrict__ mxb, const float* __restrict__ mnb,
    const float* __restrict__ msgpart, const float* __restrict__ gb1, const float* __restrict__ bb1,
    float* __restrict__ aggb, float* __restrict__ aggpart, int N)
{
    __shared__ float r1[512], r2[512];
    __shared__ float a1ms[64], c1ms[64];
    int tid = threadIdx.x, bid = blockIdx.x;
    {
        int t = tid & 63, seg = tid >> 6;
        float s = 0.f, ss = 0.f;
        for (int r = seg; r < CONV_GRID; r += 8){ s += msgpart[r*128 + t]; ss += msgpart[r*128 + 64 + t]; }
        r1[tid] = s; r2[tid] = ss;
    }
    __syncthreads();
    if (tid < 64){
        float S = 0.f, SS = 0.f;
        #pragma unroll
        for (int k=0;k<8;++k){ S += r1[tid + 64*k]; SS += r2[tid + 64*k]; }
        float invc = 1.0f/((float)N*KNB);
        float m = S*invc, var = SS*invc - m*m;
        float ai = gb1[tid]*rsqrtf(var + BN_EPS);
        a1ms[tid] = ai; c1ms[tid] = bb1[tid] - m*ai;
    }
    __syncthreads();
    int h = tid & 63;
    float ah = a1ms[h], chh = c1ms[h];
    bool useMax = (ah >= 0.f);
    float ps = 0.f, pss = 0.f;
    for (int i = bid*512 + tid; i < N*CH; i += gridDim.x*512){
        float sel = useMax ? mxb[i] : mnb[i];
        float v = leakyf(ah*sel + chh);
        aggb[i] = v; ps += v; pss += v*v;
    }
    __syncthreads();
    r1[tid] = ps; r2[tid] = pss;
    __syncthreads();
    if (tid < 64){
        float S = 0.f, SS = 0.f;
        #pragma unroll
        for (int k=0;k<8;++k){ S += r1[tid + 64*k]; SS += r2[tid + 64*k]; }
        aggpart[(size_t)bid*128 + tid]      = S;
        aggpart[(size_t)bid*128 + 64 + tid] = SS;
    }
}

// ---------- K8: fold fd2 + transform agg -> a2b2 + gram64 partials -> slabC ----------
__global__ __launch_bounds__(512) void k8_gram64t(const float* __restrict__ aggb, const float* __restrict__ aggpart,
    const float* __restrict__ gbc, const float* __restrict__ bbc,
    ushort* __restrict__ a2b2, float* __restrict__ slabC, int N)
{
    __shared__ ushort Xt[64][72];
    __shared__ float red[32][64];
    __shared__ float abncs[64], cbncs[64];
    int tid = threadIdx.x, bid = blockIdx.x;
    int wave = tid >> 6, lane = tid & 63, l15 = lane & 15, g = lane >> 4;
    const f32x4 z4 = {0.f,0.f,0.f,0.f};
    {
        float* r1 = &red[0][0]; float* r2 = r1 + 512;
        int t = tid & 63, seg = tid >> 6;
        float s = 0.f, ss = 0.f;
        for (int r = seg; r < 256; r += 8){ s += aggpart[r*128 + t]; ss += aggpart[r*128 + 64 + t]; }
        r1[tid] = s; r2[tid] = ss;
        __syncthreads();
        if (tid < 64){
            float S = 0.f, SS = 0.f;
            #pragma unroll
            for (int k=0;k<8;++k){ S += r1[tid + 64*k]; SS += r2[tid + 64*k]; }
            float invc = 1.0f/(float)N;
            float m = S*invc, var = SS*invc - m*m;
            float ai = gbc[tid]*rsqrtf(var + BN_EPS);
            abncs[tid] = ai; cbncs[tid] = bbc[tid] - m*ai;
        }
        __syncthreads();
    }
    int wr = wave >> 1, wc = wave & 1;
    f32x4 acc[2] = {z4, z4};
    float pcs[4] = {0,0,0,0};
    int nch = (N + 63) >> 6;
    for (int ch = bid; ch < nch; ch += 256){
        int base = ch << 6;
        __syncthreads();
        #pragma unroll
        for (int ii=0;ii<2;++ii){
            int i = tid + ii*512;
            int r = i >> 4, cq = i & 15;
            int n = base + r;
            float4 v = make_float4(0.f,0.f,0.f,0.f);
            if (n < N){
                v = ((const float4*)aggb)[(size_t)n*16 + cq];
                v.x = leakyf(abncs[cq*4+0]*v.x + cbncs[cq*4+0]);
                v.y = leakyf(abncs[cq*4+1]*v.y + cbncs[cq*4+1]);
                v.z = leakyf(abncs[cq*4+2]*v.z + cbncs[cq*4+2]);
                v.w = leakyf(abncs[cq*4+3]*v.w + cbncs[cq*4+3]);
            }
            uint2 pk; pk.x = cvtpk(v.x, v.y); pk.y = cvtpk(v.z, v.w);
            if (n < N) ((uint2*)a2b2)[(size_t)n*16 + cq] = pk;
            Xt[cq*4+0][r] = (ushort)(pk.x & 0xffff);
            Xt[cq*4+1][r] = (ushort)(pk.x >> 16);
            Xt[cq*4+2][r] = (ushort)(pk.y & 0xffff);
            Xt[cq*4+3][r] = (ushort)(pk.y >> 16);
            pcs[0] += v.x; pcs[1] += v.y; pcs[2] += v.z; pcs[3] += v.w;
        }
        __syncthreads();
        #pragma unroll
        for (int ks=0;ks<2;++ks){
            bf16x8 af = *(const bf16x8*)&Xt[wr*16 + l15][ks*32 + g*8];
            #pragma unroll
            for (int u=0;u<2;++u){
                bf16x8 bv = *(const bf16x8*)&Xt[wc*32 + u*16 + l15][ks*32 + g*8];
                acc[u] = __builtin_amdgcn_mfma_f32_16x16x32_bf16(af, bv, acc[u], 0,0,0);
            }
        }
    }
    float* Gp = slabC + (size_t)bid*4160;
    #pragma unroll
    for (int u=0;u<2;++u)
        #pragma unroll
        for (int q=0;q<4;++q)
            Gp[(wr*16 + g*4 + q)*CH + wc*32 + u*16 + l15] = acc[u][q];
    __syncthreads();
    { int r = tid >> 4, cq = tid & 15;
      #pragma unroll
      for (int j=0;j<4;++j) red[r][cq*4+j] = pcs[j]; }
    __syncthreads();
    if (tid < CH){
        float s = 0.f;
        #pragma unroll
        for (int k=0;k<32;++k) s += red[k][tid];
        Gp[4096 + tid] = s;
    }
}

// ---------- K10: finalize unary2 BN + wcat[:,128:192] + ccomb from reduced G2 ----------
__global__ __launch_bounds__(512) void k10_fin2(const float* __restrict__ G2, const float* __restrict__ s2,
    const float* __restrict__ Wu2, const float* __restrict__ g2, const float* __restrict__ b2,
    const float* __restrict__ cscv, float invN, ushort* __restrict__ wcat, float* __restrict__ ccomb)
{
    int gw = blockIdx.x*8 + (threadIdx.x >> 6), lane = threadIdx.x & 63;
    if (gw < 256){
        float ai, ci;
        bn_affine_wave(G2, s2, Wu2, g2, b2, invN, CH, COUT, gw, lane, ai, ci);
        wcat[gw*192 + 128 + lane] = f2bf(ai*Wu2[lane*COUT + gw]);
        if (lane == 0) ccomb[gw] = cscv[gw] + ci;
    }
}

// ---------- K11: final GEMM [feat|a2] @ wcat^T -> out ----------
__global__ __launch_bounds__(512) void final_mfma_kernel(
    const ushort* __restrict__ featbf, const ushort* __restrict__ a2b2,
    const ushort* __restrict__ wcat, const float* __restrict__ ccomb,
    float* __restrict__ out, int N)
{
    int tid = threadIdx.x, wave = tid >> 6, lane = tid & 63;
    int l15 = lane & 15, g = lane >> 4;
    int row0 = blockIdx.x*128 + wave*16;
    const f32x4 z4 = {0.f,0.f,0.f,0.f};
    f32x4 acc[16];
    #pragma unroll
    for (int i=0;i<16;++i) acc[i] = z4;
    int r = row0 + l15;
    bool ok = r < N;
    #pragma unroll
    for (int s=0;s<6;++s){
        bf16x8 af = {0,0,0,0,0,0,0,0};
        if (ok){
            const ushort* srcp = (s < 4) ? (featbf + (size_t)r*CIN + s*32 + g*8)
                                         : (a2b2  + (size_t)r*CH + (s-4)*32 + g*8);
            af = *(const bf16x8*)srcp;
        }
        #pragma unroll
        for (int nt=0;nt<16;++nt){
            bf16x8 bfr = *(const bf16x8*)(wcat + (size_t)(nt*16+l15)*192 + s*32 + g*8);
            acc[nt] = __builtin_amdgcn_mfma_f32_16x16x32_bf16(af, bfr, acc[nt], 0,0,0);
        }
    }
    #pragma unroll
    for (int nt=0;nt<16;++nt){
        float cc = ccomb[nt*16 + l15];
        #pragma unroll
        for (int q=0;q<4;++q){
            int rr = row0 + g*4 + q;
            if (rr < N) out[(size_t)rr*COUT + nt*16 + l15] = leakyf(acc[nt][q] + cc);
        }
    }
}

extern "C" void kernel_launch(void* const* d_in, const int* in_sizes, int n_in,
                              void* d_out, int out_size, void* d_ws, size_t ws_size,
                              hipStream_t stream)
{
    const float* feat = (const float*)d_in[0];
    const float* qp   = (const float*)d_in[1];
    const float* sp   = (const float*)d_in[2];
    const int*   inds = (const int*)d_in[3];
    const float* Wu1  = (const float*)d_in[4];
    const float* g1   = (const float*)d_in[5];
    const float* b1   = (const float*)d_in[6];
    const float* W0   = (const float*)d_in[7];
    const float* gb0  = (const float*)d_in[8];
    const float* bb0  = (const float*)d_in[9];
    const float* W1   = (const float*)d_in[10];
    const float* gb1  = (const float*)d_in[11];
    const float* bb1  = (const float*)d_in[12];
    const float* gbc  = (const float*)d_in[13];
    const float* bbc  = (const float*)d_in[14];
    const float* Wu2  = (const float*)d_in[15];
    const float* g2   = (const float*)d_in[16];
    const float* b2   = (const float*)d_in[17];
    const float* Wsc  = (const float*)d_in[18];
    const float* gsc  = (const float*)d_in[19];
    const float* bsc  = (const float*)d_in[20];

    const int N = in_sizes[0] / CIN;           // 20000

    float* ws   = (float*)d_ws;
    float* XtX  = ws;                              // 16384 + 128
    float* fsum = ws + 16384;
    float* G0   = ws + 16512;                      // 4096 + 64
    float* s0   = G0 + 4096;
    float* G2   = ws + 16512 + 4160;               // 4096 + 64
    float* s2   = G2 + 4096;
    float* cnt  = ws + 16512 + 8320;               // N
    float* prm  = cnt + N;                         // 1536
    float* c1v  = prm + 64;
    float* c0p  = prm + 192;
    float* cscv = prm + 768;
    float* msgpart = prm + 1536;                   // CONV_GRID*128
    float* aggpart = msgpart + CONV_GRID*128;      // 256*128
    float* mxb  = aggpart + 256*128;               // N*64
    float* mnb  = mxb + (size_t)N*CH;              // N*64
    float* aggb = mnb + (size_t)N*CH;              // N*64
    ushort* xbf    = (ushort*)(aggb + (size_t)N*CH);
    ushort* featbf = xbf + (size_t)(N+1)*CH;
    ushort* a2b2   = featbf + (size_t)N*CIN;
    ushort* w1s    = a2b2 + (size_t)N*CH;          // 192*64
    ushort* wcat   = w1s + 192*CH;                 // 256*192
    ushort* w1t    = wcat + COUT*192;              // 64*128
    ushort* w0t    = w1t + CH*CIN;                 // 64*64
    float*  ccomb  = (float*)(w0t + CH*CH);        // 256

    // slab aliasing (stream-order safe):
    float* slabA = mxb;     // 128*16512 <= 2*N*CH   (dead until conv writes mx/mn)
    float* slabB = aggb;    // 157*4160  <= N*CH     (dead until k7 writes aggb)
    float* slabC = mxb;     // 256*4160  <= N*CH     (mxb consumed by k7 before k8)

    const int nTiles = (N + 127)/128;              // 157

    hipMemsetAsync(cnt, 0, (size_t)N*sizeof(float), stream);
    k1_kernel<<<256, 512, 0, stream>>>(feat, inds, W1, N, slabA, featbf, w1s, xbf, cnt);
    reduce_slab<<<(16512 + 255)/256, 256, 0, stream>>>(slabA, 128, 16512, XtX);
    k3_finA<<<40, 512, 0, stream>>>(XtX, fsum, Wu1, g1, b1, Wsc, gsc, bsc, 1.0f/N, c1v, w1t, wcat, cscv);
    k4_unary1_gram<<<nTiles, 512, 0, stream>>>(featbf, w1t, c1v, cnt, xbf, slabB, N);
    reduce_slab<<<(4160 + 255)/256, 256, 0, stream>>>(slabB, nTiles, 4160, G0);
    k5_fin0<<<8, 512, 0, stream>>>(G0, s0, W0, gb0, bb0, 1.0f/((float)N*KNB), c0p, w0t);
    conv_msg_mfma<<<CONV_GRID, 512, 0, stream>>>(xbf, qp, sp, inds, w0t, w1s, c0p, mxb, mnb, msgpart, N);
    k7_agg<<<256, 512, 0, stream>>>(mxb, mnb, msgpart, gb1, bb1, aggb, aggpart, N);
    k8_gram64t<<<256, 512, 0, stream>>>(aggb, aggpart, gbc, bbc, a2b2, slabC, N);
    reduce_slab<<<(4160 + 255)/256, 256, 0, stream>>>(slabC, 256, 4160, G2);
    k10_fin2<<<32, 512, 0, stream>>>(G2, s2, Wu2, g2, b2, cscv, 1.0f/N, wcat, ccomb);
    final_mfma_kernel<<<nTiles, 512, 0, stream>>>(featbf, a2b2, wcat, ccomb, (float*)d_out, N);
}